// Round 1
// baseline (1256.225 us; speedup 1.0000x reference)
//
#include <hip/hip_runtime.h>
#include <math.h>

#define M_TOK 4096           // B*S
#define HID   2048
#define NEXP  8
#define CAP   1536
#define DISP_ELEMS 50331648ull   // 4096*8*1536

// ---------------------------------------------------------------------------
// GEMM: C = relu(A @ B + bias). A: M x K row-major, B: K x N row-major.
// Tile 128x128, BK=16, 256 threads, 8x8 micro-tile per thread. fp32 vector FMA.
// ---------------------------------------------------------------------------
__global__ __launch_bounds__(256)
void gemm_relu_k(const float* __restrict__ A, const float* __restrict__ B,
                 const float* __restrict__ bias, float* __restrict__ C,
                 int N, int K) {
  __shared__ float As[16][128];
  __shared__ float Bs[16][128];
  const int tid = threadIdx.x;
  const int tx = tid & 15, ty = tid >> 4;
  const int row0 = blockIdx.y * 128, col0 = blockIdx.x * 128;

  float acc[8][8];
#pragma unroll
  for (int i = 0; i < 8; ++i)
#pragma unroll
    for (int j = 0; j < 8; ++j) acc[i][j] = 0.f;

  for (int k0 = 0; k0 < K; k0 += 16) {
#pragma unroll
    for (int it = 0; it < 2; ++it) {
      int idx = tid + it * 256;
      int r = idx >> 2, kq = idx & 3;
      float4 v = *reinterpret_cast<const float4*>(
          &A[(size_t)(row0 + r) * K + k0 + kq * 4]);
      As[kq * 4 + 0][r] = v.x;
      As[kq * 4 + 1][r] = v.y;
      As[kq * 4 + 2][r] = v.z;
      As[kq * 4 + 3][r] = v.w;
    }
#pragma unroll
    for (int it = 0; it < 2; ++it) {
      int idx = tid + it * 256;
      int r = idx >> 5, cq = idx & 31;
      float4 v = *reinterpret_cast<const float4*>(
          &B[(size_t)(k0 + r) * N + col0 + cq * 4]);
      *reinterpret_cast<float4*>(&Bs[r][cq * 4]) = v;
    }
    __syncthreads();
#pragma unroll
    for (int kk = 0; kk < 16; ++kk) {
      float a[8], b[8];
#pragma unroll
      for (int i = 0; i < 8; ++i) a[i] = As[kk][ty * 8 + i];
#pragma unroll
      for (int j = 0; j < 8; ++j) b[j] = Bs[kk][tx * 8 + j];
#pragma unroll
      for (int i = 0; i < 8; ++i)
#pragma unroll
        for (int j = 0; j < 8; ++j) acc[i][j] = fmaf(a[i], b[j], acc[i][j]);
    }
    __syncthreads();
  }
#pragma unroll
  for (int i = 0; i < 8; ++i) {
    int r = row0 + ty * 8 + i;
#pragma unroll
    for (int j = 0; j < 8; j += 4) {
      int c = col0 + tx * 8 + j;
      float4 o;
      o.x = fmaxf(acc[i][j + 0] + bias[c + 0], 0.f);
      o.y = fmaxf(acc[i][j + 1] + bias[c + 1], 0.f);
      o.z = fmaxf(acc[i][j + 2] + bias[c + 2], 0.f);
      o.w = fmaxf(acc[i][j + 3] + bias[c + 3], 0.f);
      *reinterpret_cast<float4*>(&C[(size_t)r * N + c]) = o;
    }
  }
}

// ---------------------------------------------------------------------------
// Per-token second layers + softmax + top-1 flag.
// One block (256 threads) per token.
// ---------------------------------------------------------------------------
__global__ __launch_bounds__(256)
void router_k(const float* __restrict__ h_i, const float* __restrict__ h_r,
              const float* __restrict__ h_u,
              const float* __restrict__ Wi2, const float* __restrict__ bi2,
              const float* __restrict__ Wr2, const float* __restrict__ br2,
              const float* __restrict__ Wu2, const float* __restrict__ bu2,
              float* __restrict__ router_probs, float* __restrict__ importance,
              int* __restrict__ expert_used) {
  const int t = blockIdx.x;
  const int tid = threadIdx.x;

  // importance layer 2: dot(h_i[t, :1024], Wi2)
  float acc_i;
  {
    float4 hv = *reinterpret_cast<const float4*>(&h_i[(size_t)t * 1024 + tid * 4]);
    float4 wv = *reinterpret_cast<const float4*>(&Wi2[tid * 4]);
    acc_i = hv.x * wv.x + hv.y * wv.y + hv.z * wv.z + hv.w * wv.w;
  }

  float accR[8], accU[8];
#pragma unroll
  for (int e = 0; e < 8; ++e) { accR[e] = 0.f; accU[e] = 0.f; }

  const int i0 = tid * 8;
  {
    float4 h0 = *reinterpret_cast<const float4*>(&h_r[(size_t)t * 2048 + i0]);
    float4 h1 = *reinterpret_cast<const float4*>(&h_r[(size_t)t * 2048 + i0 + 4]);
    float hr[8] = {h0.x, h0.y, h0.z, h0.w, h1.x, h1.y, h1.z, h1.w};
#pragma unroll
    for (int q = 0; q < 8; ++q) {
      float4 w0 = *reinterpret_cast<const float4*>(&Wr2[(size_t)(i0 + q) * 8]);
      float4 w1 = *reinterpret_cast<const float4*>(&Wr2[(size_t)(i0 + q) * 8 + 4]);
      accR[0] = fmaf(hr[q], w0.x, accR[0]);
      accR[1] = fmaf(hr[q], w0.y, accR[1]);
      accR[2] = fmaf(hr[q], w0.z, accR[2]);
      accR[3] = fmaf(hr[q], w0.w, accR[3]);
      accR[4] = fmaf(hr[q], w1.x, accR[4]);
      accR[5] = fmaf(hr[q], w1.y, accR[5]);
      accR[6] = fmaf(hr[q], w1.z, accR[6]);
      accR[7] = fmaf(hr[q], w1.w, accR[7]);
    }
  }
  {
    float4 h0 = *reinterpret_cast<const float4*>(&h_u[(size_t)t * 2048 + i0]);
    float4 h1 = *reinterpret_cast<const float4*>(&h_u[(size_t)t * 2048 + i0 + 4]);
    float hu[8] = {h0.x, h0.y, h0.z, h0.w, h1.x, h1.y, h1.z, h1.w};
#pragma unroll
    for (int q = 0; q < 8; ++q) {
      float4 w0 = *reinterpret_cast<const float4*>(&Wu2[(size_t)(i0 + q) * 8]);
      float4 w1 = *reinterpret_cast<const float4*>(&Wu2[(size_t)(i0 + q) * 8 + 4]);
      accU[0] = fmaf(hu[q], w0.x, accU[0]);
      accU[1] = fmaf(hu[q], w0.y, accU[1]);
      accU[2] = fmaf(hu[q], w0.z, accU[2]);
      accU[3] = fmaf(hu[q], w0.w, accU[3]);
      accU[4] = fmaf(hu[q], w1.x, accU[4]);
      accU[5] = fmaf(hu[q], w1.y, accU[5]);
      accU[6] = fmaf(hu[q], w1.z, accU[6]);
      accU[7] = fmaf(hu[q], w1.w, accU[7]);
    }
  }

  float vals[17];
  vals[0] = acc_i;
#pragma unroll
  for (int e = 0; e < 8; ++e) { vals[1 + e] = accR[e]; vals[9 + e] = accU[e]; }
#pragma unroll
  for (int k = 0; k < 17; ++k) {
    float v = vals[k];
    v += __shfl_xor(v, 1);
    v += __shfl_xor(v, 2);
    v += __shfl_xor(v, 4);
    v += __shfl_xor(v, 8);
    v += __shfl_xor(v, 16);
    v += __shfl_xor(v, 32);
    vals[k] = v;
  }
  __shared__ float red[4][17];
  const int lane = tid & 63, wid = tid >> 6;
  if (lane == 0) {
#pragma unroll
    for (int k = 0; k < 17; ++k) red[wid][k] = vals[k];
  }
  __syncthreads();
  if (tid == 0) {
    float s[17];
#pragma unroll
    for (int k = 0; k < 17; ++k)
      s[k] = red[0][k] + red[1][k] + red[2][k] + red[3][k];
    float impLogit = s[0] + bi2[0];
    float imp = 1.f / (1.f + expf(-impLogit));
    importance[t] = imp;
    bool useImp = imp > 0.5f;
    float logits[8];
#pragma unroll
    for (int e = 0; e < 8; ++e)
      logits[e] = useImp ? (s[1 + e] + br2[e]) : (s[9 + e] + bu2[e]);
    float mx = logits[0];
#pragma unroll
    for (int e = 1; e < 8; ++e) mx = fmaxf(mx, logits[e]);
    float ex[8], sum = 0.f;
#pragma unroll
    for (int e = 0; e < 8; ++e) { ex[e] = expf(logits[e] - mx); sum += ex[e]; }
    float p[8];
#pragma unroll
    for (int e = 0; e < 8; ++e) p[e] = ex[e] / sum;
#pragma unroll
    for (int e = 0; e < 8; ++e) router_probs[(size_t)t * 8 + e] = p[e];
    int e1 = 0; float p1 = p[0];
#pragma unroll
    for (int e = 1; e < 8; ++e) if (p[e] > p1) { p1 = p[e]; e1 = e; }
    expert_used[e1] = 1;   // benign race: all writers store 1 -> deterministic
  }
}

// ---------------------------------------------------------------------------
// Scatter: per token write the 2 nonzeros of disp and comb.
// ---------------------------------------------------------------------------
__global__ __launch_bounds__(256)
void scatter_k(const float* __restrict__ router_probs,
               const int* __restrict__ expert_used,
               float* __restrict__ disp, float* __restrict__ comb) {
  int t = blockIdx.x * blockDim.x + threadIdx.x;
  if (t >= M_TOK) return;
  float4 a = *reinterpret_cast<const float4*>(&router_probs[(size_t)t * 8]);
  float4 b = *reinterpret_cast<const float4*>(&router_probs[(size_t)t * 8 + 4]);
  float p[8] = {a.x, a.y, a.z, a.w, b.x, b.y, b.z, b.w};
  int e1 = 0; float p1 = p[0];
#pragma unroll
  for (int e = 1; e < 8; ++e) if (p[e] > p1) { p1 = p[e]; e1 = e; }
  int e2 = 0; float p2 = -1.f;
#pragma unroll
  for (int e = 0; e < 8; ++e) {
    if (e == e1) continue;
    if (p[e] > p2) { p2 = p[e]; e2 = e; }
  }
  float s = p1 + p2;
  float p1n = p1 / s, p2n = p2 / s;
  size_t base = (size_t)t * NEXP * CAP;
  disp[base + (size_t)e1 * CAP + 0] = 1.f;
  comb[base + (size_t)e1 * CAP + 0] = p1n;
  int pos = expert_used[e2];           // occ after top-1 pass: 0 or 1
  disp[base + (size_t)e2 * CAP + pos] = 1.f;
  comb[base + (size_t)e2 * CAP + pos] = p2n;
}

// ---------------------------------------------------------------------------
// Aux loss: deterministic single-block reduction over 4096 tokens.
// ---------------------------------------------------------------------------
__global__ __launch_bounds__(256)
void aux_k(const float* __restrict__ router_probs,
           const float* __restrict__ importance, float* __restrict__ aux_out) {
  const int tid = threadIdx.x;
  float s8[8], m8[8];
#pragma unroll
  for (int e = 0; e < 8; ++e) { s8[e] = 0.f; m8[e] = 0.f; }
  for (int t = tid; t < M_TOK; t += 256) {
    float4 a = *reinterpret_cast<const float4*>(&router_probs[(size_t)t * 8]);
    float4 b = *reinterpret_cast<const float4*>(&router_probs[(size_t)t * 8 + 4]);
    float mk = importance[t] > 0.5f ? 1.f : 0.f;
    s8[0] += a.x; s8[1] += a.y; s8[2] += a.z; s8[3] += a.w;
    s8[4] += b.x; s8[5] += b.y; s8[6] += b.z; s8[7] += b.w;
    m8[0] += a.x * mk; m8[1] += a.y * mk; m8[2] += a.z * mk; m8[3] += a.w * mk;
    m8[4] += b.x * mk; m8[5] += b.y * mk; m8[6] += b.z * mk; m8[7] += b.w * mk;
  }
  float vals[16];
#pragma unroll
  for (int e = 0; e < 8; ++e) { vals[e] = s8[e]; vals[8 + e] = m8[e]; }
#pragma unroll
  for (int k = 0; k < 16; ++k) {
    float v = vals[k];
    v += __shfl_xor(v, 1);
    v += __shfl_xor(v, 2);
    v += __shfl_xor(v, 4);
    v += __shfl_xor(v, 8);
    v += __shfl_xor(v, 16);
    v += __shfl_xor(v, 32);
    vals[k] = v;
  }
  __shared__ float red[4][16];
  const int lane = tid & 63, wid = tid >> 6;
  if (lane == 0) {
#pragma unroll
    for (int k = 0; k < 16; ++k) red[wid][k] = vals[k];
  }
  __syncthreads();
  if (tid == 0) {
    float s[16];
#pragma unroll
    for (int k = 0; k < 16; ++k)
      s[k] = red[0][k] + red[1][k] + red[2][k] + red[3][k];
    float entropy_loss = 0.f;
#pragma unroll
    for (int e = 0; e < 8; ++e) {
      float rppe = s[e] / (float)M_TOK;
      entropy_loss += rppe * logf(rppe * 8.f + 1e-9f);
    }
    float tot = 0.f;
#pragma unroll
    for (int e = 0; e < 8; ++e) tot += s[8 + e] + 1e-9f;
    float imp_entropy = 0.f;
#pragma unroll
    for (int e = 0; e < 8; ++e) {
      float ipe = (s[8 + e] + 1e-9f) / tot;
      imp_entropy -= ipe * logf(ipe + 1e-9f);
    }
    aux_out[0] = entropy_loss - 0.1f * (imp_entropy / logf(8.f));
  }
}

// ---------------------------------------------------------------------------
extern "C" void kernel_launch(void* const* d_in, const int* in_sizes, int n_in,
                              void* d_out, int out_size, void* d_ws,
                              size_t ws_size, hipStream_t stream) {
  const float* x   = (const float*)d_in[0];
  const float* Wi1 = (const float*)d_in[1];
  const float* bi1 = (const float*)d_in[2];
  const float* Wi2 = (const float*)d_in[3];
  const float* bi2 = (const float*)d_in[4];
  const float* Wr1 = (const float*)d_in[5];
  const float* br1 = (const float*)d_in[6];
  const float* Wr2 = (const float*)d_in[7];
  const float* br2 = (const float*)d_in[8];
  const float* Wu1 = (const float*)d_in[9];
  const float* bu1 = (const float*)d_in[10];
  const float* Wu2 = (const float*)d_in[11];
  const float* bu2 = (const float*)d_in[12];

  float* out  = (float*)d_out;
  float* disp = out;
  float* comb = out + DISP_ELEMS;
  float* rp   = out + 2 * DISP_ELEMS;            // 32768
  float* aux  = out + 2 * DISP_ELEMS + 32768;    // 1
  float* imp  = aux + 1;                         // 4096

  // Scratch plan. h activations: d_ws if big enough, else front of comb
  // region (84 MB < 201 MB; comb is memset AFTER h is consumed).
  // Expert flags: last 16 floats of comb region (never touched by scatter,
  // zeroed at the very end) -> zero dependence on ws_size.
  const size_t hi_n = (size_t)M_TOK * 1024;
  const size_t hr_n = (size_t)M_TOK * 2048;
  const size_t hu_n = (size_t)M_TOK * 2048;
  const size_t need = (hi_n + hr_n + hu_n) * sizeof(float) + 256;
  float *h_i, *h_r, *h_u;
  if (ws_size >= need) {
    h_i = (float*)((char*)d_ws + 256);
  } else {
    h_i = comb;
  }
  h_r = h_i + hi_n;
  h_u = h_r + hr_n;
  int* flags = (int*)(comb + DISP_ELEMS - 16);

  // 1. zero disp (full region) and the flags
  hipMemsetAsync(disp, 0, DISP_ELEMS * sizeof(float), stream);
  hipMemsetAsync(flags, 0, 16 * sizeof(float), stream);

  // 2. the three layer-1 GEMMs
  gemm_relu_k<<<dim3(1024 / 128, M_TOK / 128), 256, 0, stream>>>(
      x, Wi1, bi1, h_i, 1024, HID);
  gemm_relu_k<<<dim3(2048 / 128, M_TOK / 128), 256, 0, stream>>>(
      x, Wr1, br1, h_r, 2048, HID);
  gemm_relu_k<<<dim3(2048 / 128, M_TOK / 128), 256, 0, stream>>>(
      x, Wu1, bu1, h_u, 2048, HID);

  // 3. per-token router: probs, importance, expert top-1 flags
  router_k<<<M_TOK, 256, 0, stream>>>(h_i, h_r, h_u, Wi2, bi2, Wr2, br2,
                                      Wu2, bu2, rp, imp, flags);

  // 4. zero comb region except the flag tail (h in comb is dead now)
  hipMemsetAsync(comb, 0, (DISP_ELEMS - 16) * sizeof(float), stream);

  // 5. scatter the 2 nonzeros per token
  scatter_k<<<(M_TOK + 255) / 256, 256, 0, stream>>>(rp, flags, disp, comb);

  // 6. zero the flag tail so comb is fully correct
  hipMemsetAsync(flags, 0, 16 * sizeof(float), stream);

  // 7. aux loss
  aux_k<<<1, 256, 0, stream>>>(rp, imp, aux);
}

// Round 2
// 461.808 us; speedup vs baseline: 2.7202x; 2.7202x over previous
//
#include <hip/hip_runtime.h>
#include <math.h>

#define M_TOK 4096           // B*S
#define HID   2048
#define NEXP  8
#define CAP   1536
#define DISP_ELEMS 50331648ull   // 4096*8*1536
#define NTOT  5120               // 1024 + 2048 + 2048 (concat N)

typedef __attribute__((ext_vector_type(8))) short bf16x8;
typedef __attribute__((ext_vector_type(4))) float f32x4;

__device__ __forceinline__ unsigned short f2bf(float f) {
  unsigned u = __float_as_uint(f);
  unsigned r = u + 0x7FFFu + ((u >> 16) & 1u);   // RNE (finite inputs)
  return (unsigned short)(r >> 16);
}
__device__ __forceinline__ float bf2f(unsigned short h) {
  return __uint_as_float(((unsigned)h) << 16);
}

__device__ __forceinline__ void gload16(const void* g, void* l) {
  __builtin_amdgcn_global_load_lds(
      (const __attribute__((address_space(1))) void*)g,
      (__attribute__((address_space(3))) void*)l, 16, 0, 0);
}

// ---------------------------------------------------------------------------
// x (fp32 [M][K]) -> x_hi, x_lo (bf16 [M][K])
// ---------------------------------------------------------------------------
__global__ __launch_bounds__(256)
void convert_x_k(const float* __restrict__ x, unsigned short* __restrict__ xh,
                 unsigned short* __restrict__ xl) {
  size_t i = ((size_t)blockIdx.x * 256 + threadIdx.x) * 4;
  float4 v = *reinterpret_cast<const float4*>(&x[i]);
  float f[4] = {v.x, v.y, v.z, v.w};
  unsigned short hh[4], ll[4];
#pragma unroll
  for (int j = 0; j < 4; ++j) {
    hh[j] = f2bf(f[j]);
    ll[j] = f2bf(f[j] - bf2f(hh[j]));
  }
  uint2 ph, pl;
  ph.x = hh[0] | ((unsigned)hh[1] << 16); ph.y = hh[2] | ((unsigned)hh[3] << 16);
  pl.x = ll[0] | ((unsigned)ll[1] << 16); pl.y = ll[2] | ((unsigned)ll[3] << 16);
  *reinterpret_cast<uint2*>(&xh[i]) = ph;
  *reinterpret_cast<uint2*>(&xl[i]) = pl;
}

// ---------------------------------------------------------------------------
// W (fp32 [K=2048][N]) -> W^T hi/lo (bf16 [rowOff+N][2048])
// ---------------------------------------------------------------------------
__global__ __launch_bounds__(256)
void convert_wT_k(const float* __restrict__ W, int N, int rowOff,
                  unsigned short* __restrict__ wTh,
                  unsigned short* __restrict__ wTl) {
  __shared__ float tile[32][33];
  const int k0 = blockIdx.y * 32;
  const int n0 = blockIdx.x * 32;
  const int tid = threadIdx.x;
  {
    int r = tid >> 3, c4 = (tid & 7) * 4;
    float4 v = *reinterpret_cast<const float4*>(&W[(size_t)(k0 + r) * N + n0 + c4]);
    tile[r][c4 + 0] = v.x; tile[r][c4 + 1] = v.y;
    tile[r][c4 + 2] = v.z; tile[r][c4 + 3] = v.w;
  }
  __syncthreads();
  int n = tid >> 3, kc = (tid & 7) * 4;
  unsigned short hh[4], ll[4];
#pragma unroll
  for (int j = 0; j < 4; ++j) {
    float f = tile[kc + j][n];
    hh[j] = f2bf(f);
    ll[j] = f2bf(f - bf2f(hh[j]));
  }
  size_t o = (size_t)(rowOff + n0 + n) * HID + k0 + kc;
  uint2 ph, pl;
  ph.x = hh[0] | ((unsigned)hh[1] << 16); ph.y = hh[2] | ((unsigned)hh[3] << 16);
  pl.x = ll[0] | ((unsigned)ll[1] << 16); pl.y = ll[2] | ((unsigned)ll[3] << 16);
  *reinterpret_cast<uint2*>(&wTh[o]) = ph;
  *reinterpret_cast<uint2*>(&wTl[o]) = pl;
}

// ---------------------------------------------------------------------------
// Split-bf16 GEMM: C = relu(A@W + b), A fp32-split (Ah+Al), W^T-split rows.
// 128x128 tile, BK=32, 256 thr (4 waves 2x2), 48 MFMA/wave/K-step.
// C = Ah@Bh + Ah@Bl + Al@Bh   (fp32 accum; lo*lo dropped ~2^-18)
// ---------------------------------------------------------------------------
__global__ __launch_bounds__(256)
void gemm_split_k(const unsigned short* __restrict__ Ah,
                  const unsigned short* __restrict__ Al,
                  const unsigned short* __restrict__ Bh,
                  const unsigned short* __restrict__ Bl,
                  const float* __restrict__ bi1, const float* __restrict__ br1,
                  const float* __restrict__ bu1, float* __restrict__ h_i,
                  float* __restrict__ h_r, float* __restrict__ h_u) {
  __shared__ unsigned short lds[16384];  // AH@0 AL@4096 BH@8192 BL@12288 (shorts)
  const int tid = threadIdx.x;
  const int lane = tid & 63;
  const int wave = tid >> 6;
  const int wr = wave >> 1, wc = wave & 1;
  const int ct = blockIdx.x;            // 0..39 col tile in concat-N
  const int row0 = blockIdx.y * 128;
  const int bcol0 = ct * 128;           // row in W^T concat

  f32x4 acc[4][4];
#pragma unroll
  for (int m = 0; m < 4; ++m)
#pragma unroll
    for (int n = 0; n < 4; ++n) acc[m][n] = (f32x4){0.f, 0.f, 0.f, 0.f};

  for (int k0 = 0; k0 < HID; k0 += 32) {
#pragma unroll
    for (int it = 0; it < 2; ++it) {
      int ix = it * 256 + tid;
      int r = ix >> 2, c16 = ix & 3;
      size_t ga = (size_t)(row0 + r) * HID + k0 + c16 * 8;
      size_t gb = (size_t)(bcol0 + r) * HID + k0 + c16 * 8;
      gload16(Ah + ga, &lds[ix * 8]);
      gload16(Al + ga, &lds[4096 + ix * 8]);
      gload16(Bh + gb, &lds[8192 + ix * 8]);
      gload16(Bl + gb, &lds[12288 + ix * 8]);
    }
    __syncthreads();   // compiler drains vmcnt(0) before s_barrier

    bf16x8 ah[4], al[4], bh[4], bl[4];
    const int kk = (lane >> 4) * 8;
#pragma unroll
    for (int m = 0; m < 4; ++m) {
      int rr = wr * 64 + m * 16 + (lane & 15);
      ah[m] = *reinterpret_cast<const bf16x8*>(&lds[rr * 32 + kk]);
      al[m] = *reinterpret_cast<const bf16x8*>(&lds[4096 + rr * 32 + kk]);
    }
#pragma unroll
    for (int n = 0; n < 4; ++n) {
      int cc = wc * 64 + n * 16 + (lane & 15);
      bh[n] = *reinterpret_cast<const bf16x8*>(&lds[8192 + cc * 32 + kk]);
      bl[n] = *reinterpret_cast<const bf16x8*>(&lds[12288 + cc * 32 + kk]);
    }
#pragma unroll
    for (int m = 0; m < 4; ++m)
#pragma unroll
      for (int n = 0; n < 4; ++n) {
        acc[m][n] = __builtin_amdgcn_mfma_f32_16x16x32_bf16(ah[m], bh[n], acc[m][n], 0, 0, 0);
        acc[m][n] = __builtin_amdgcn_mfma_f32_16x16x32_bf16(ah[m], bl[n], acc[m][n], 0, 0, 0);
        acc[m][n] = __builtin_amdgcn_mfma_f32_16x16x32_bf16(al[m], bh[n], acc[m][n], 0, 0, 0);
      }
    __syncthreads();
  }

  float* C; const float* bias; int ldc, col0l;
  if (ct < 8)       { C = h_i; bias = bi1; ldc = 1024; col0l = ct * 128; }
  else if (ct < 24) { C = h_r; bias = br1; ldc = 2048; col0l = (ct - 8) * 128; }
  else              { C = h_u; bias = bu1; ldc = 2048; col0l = (ct - 24) * 128; }
#pragma unroll
  for (int n = 0; n < 4; ++n) {
    int cg = col0l + wc * 64 + n * 16 + (lane & 15);
    float bn = bias[cg];
#pragma unroll
    for (int m = 0; m < 4; ++m) {
      int rbase = row0 + wr * 64 + m * 16 + (lane >> 4) * 4;
#pragma unroll
      for (int j = 0; j < 4; ++j)
        C[(size_t)(rbase + j) * ldc + cg] = fmaxf(acc[m][n][j] + bn, 0.f);
    }
  }
}

// ---------------------------------------------------------------------------
// Per-token second layers + softmax + top-1 flag. One block per token.
// ---------------------------------------------------------------------------
__global__ __launch_bounds__(256)
void router_k(const float* __restrict__ h_i, const float* __restrict__ h_r,
              const float* __restrict__ h_u,
              const float* __restrict__ Wi2, const float* __restrict__ bi2,
              const float* __restrict__ Wr2, const float* __restrict__ br2,
              const float* __restrict__ Wu2, const float* __restrict__ bu2,
              float* __restrict__ router_probs, float* __restrict__ importance,
              int* __restrict__ expert_used) {
  const int t = blockIdx.x;
  const int tid = threadIdx.x;

  float acc_i;
  {
    float4 hv = *reinterpret_cast<const float4*>(&h_i[(size_t)t * 1024 + tid * 4]);
    float4 wv = *reinterpret_cast<const float4*>(&Wi2[tid * 4]);
    acc_i = hv.x * wv.x + hv.y * wv.y + hv.z * wv.z + hv.w * wv.w;
  }

  float accR[8], accU[8];
#pragma unroll
  for (int e = 0; e < 8; ++e) { accR[e] = 0.f; accU[e] = 0.f; }

  const int i0 = tid * 8;
  {
    float4 h0 = *reinterpret_cast<const float4*>(&h_r[(size_t)t * 2048 + i0]);
    float4 h1 = *reinterpret_cast<const float4*>(&h_r[(size_t)t * 2048 + i0 + 4]);
    float hr[8] = {h0.x, h0.y, h0.z, h0.w, h1.x, h1.y, h1.z, h1.w};
#pragma unroll
    for (int q = 0; q < 8; ++q) {
      float4 w0 = *reinterpret_cast<const float4*>(&Wr2[(size_t)(i0 + q) * 8]);
      float4 w1 = *reinterpret_cast<const float4*>(&Wr2[(size_t)(i0 + q) * 8 + 4]);
      accR[0] = fmaf(hr[q], w0.x, accR[0]); accR[1] = fmaf(hr[q], w0.y, accR[1]);
      accR[2] = fmaf(hr[q], w0.z, accR[2]); accR[3] = fmaf(hr[q], w0.w, accR[3]);
      accR[4] = fmaf(hr[q], w1.x, accR[4]); accR[5] = fmaf(hr[q], w1.y, accR[5]);
      accR[6] = fmaf(hr[q], w1.z, accR[6]); accR[7] = fmaf(hr[q], w1.w, accR[7]);
    }
  }
  {
    float4 h0 = *reinterpret_cast<const float4*>(&h_u[(size_t)t * 2048 + i0]);
    float4 h1 = *reinterpret_cast<const float4*>(&h_u[(size_t)t * 2048 + i0 + 4]);
    float hu[8] = {h0.x, h0.y, h0.z, h0.w, h1.x, h1.y, h1.z, h1.w};
#pragma unroll
    for (int q = 0; q < 8; ++q) {
      float4 w0 = *reinterpret_cast<const float4*>(&Wu2[(size_t)(i0 + q) * 8]);
      float4 w1 = *reinterpret_cast<const float4*>(&Wu2[(size_t)(i0 + q) * 8 + 4]);
      accU[0] = fmaf(hu[q], w0.x, accU[0]); accU[1] = fmaf(hu[q], w0.y, accU[1]);
      accU[2] = fmaf(hu[q], w0.z, accU[2]); accU[3] = fmaf(hu[q], w0.w, accU[3]);
      accU[4] = fmaf(hu[q], w1.x, accU[4]); accU[5] = fmaf(hu[q], w1.y, accU[5]);
      accU[6] = fmaf(hu[q], w1.z, accU[6]); accU[7] = fmaf(hu[q], w1.w, accU[7]);
    }
  }

  float vals[17];
  vals[0] = acc_i;
#pragma unroll
  for (int e = 0; e < 8; ++e) { vals[1 + e] = accR[e]; vals[9 + e] = accU[e]; }
#pragma unroll
  for (int k = 0; k < 17; ++k) {
    float v = vals[k];
    v += __shfl_xor(v, 1);  v += __shfl_xor(v, 2);  v += __shfl_xor(v, 4);
    v += __shfl_xor(v, 8);  v += __shfl_xor(v, 16); v += __shfl_xor(v, 32);
    vals[k] = v;
  }
  __shared__ float red[4][17];
  const int lane = tid & 63, wid = tid >> 6;
  if (lane == 0) {
#pragma unroll
    for (int k = 0; k < 17; ++k) red[wid][k] = vals[k];
  }
  __syncthreads();
  if (tid == 0) {
    float s[17];
#pragma unroll
    for (int k = 0; k < 17; ++k)
      s[k] = red[0][k] + red[1][k] + red[2][k] + red[3][k];
    float imp = 1.f / (1.f + expf(-(s[0] + bi2[0])));
    importance[t] = imp;
    bool useImp = imp > 0.5f;
    float logits[8];
#pragma unroll
    for (int e = 0; e < 8; ++e)
      logits[e] = useImp ? (s[1 + e] + br2[e]) : (s[9 + e] + bu2[e]);
    float mx = logits[0];
#pragma unroll
    for (int e = 1; e < 8; ++e) mx = fmaxf(mx, logits[e]);
    float ex[8], sum = 0.f;
#pragma unroll
    for (int e = 0; e < 8; ++e) { ex[e] = expf(logits[e] - mx); sum += ex[e]; }
    float p[8];
#pragma unroll
    for (int e = 0; e < 8; ++e) p[e] = ex[e] / sum;
#pragma unroll
    for (int e = 0; e < 8; ++e) router_probs[(size_t)t * 8 + e] = p[e];
    int e1 = 0; float p1 = p[0];
#pragma unroll
    for (int e = 1; e < 8; ++e) if (p[e] > p1) { p1 = p[e]; e1 = e; }
    expert_used[e1] = 1;   // benign race: all writers store 1
  }
}

// ---------------------------------------------------------------------------
__global__ __launch_bounds__(256)
void scatter_k(const float* __restrict__ router_probs,
               const int* __restrict__ expert_used,
               float* __restrict__ disp, float* __restrict__ comb) {
  int t = blockIdx.x * blockDim.x + threadIdx.x;
  if (t >= M_TOK) return;
  float4 a = *reinterpret_cast<const float4*>(&router_probs[(size_t)t * 8]);
  float4 b = *reinterpret_cast<const float4*>(&router_probs[(size_t)t * 8 + 4]);
  float p[8] = {a.x, a.y, a.z, a.w, b.x, b.y, b.z, b.w};
  int e1 = 0; float p1 = p[0];
#pragma unroll
  for (int e = 1; e < 8; ++e) if (p[e] > p1) { p1 = p[e]; e1 = e; }
  int e2 = 0; float p2 = -1.f;
#pragma unroll
  for (int e = 0; e < 8; ++e) {
    if (e == e1) continue;
    if (p[e] > p2) { p2 = p[e]; e2 = e; }
  }
  float s = p1 + p2;
  float p1n = p1 / s, p2n = p2 / s;
  size_t base = (size_t)t * NEXP * CAP;
  disp[base + (size_t)e1 * CAP + 0] = 1.f;
  comb[base + (size_t)e1 * CAP + 0] = p1n;
  int pos = expert_used[e2];
  disp[base + (size_t)e2 * CAP + pos] = 1.f;
  comb[base + (size_t)e2 * CAP + pos] = p2n;
}

// ---------------------------------------------------------------------------
__global__ __launch_bounds__(256)
void aux_k(const float* __restrict__ router_probs,
           const float* __restrict__ importance, float* __restrict__ aux_out) {
  const int tid = threadIdx.x;
  float s8[8], m8[8];
#pragma unroll
  for (int e = 0; e < 8; ++e) { s8[e] = 0.f; m8[e] = 0.f; }
  for (int t = tid; t < M_TOK; t += 256) {
    float4 a = *reinterpret_cast<const float4*>(&router_probs[(size_t)t * 8]);
    float4 b = *reinterpret_cast<const float4*>(&router_probs[(size_t)t * 8 + 4]);
    float mk = importance[t] > 0.5f ? 1.f : 0.f;
    s8[0] += a.x; s8[1] += a.y; s8[2] += a.z; s8[3] += a.w;
    s8[4] += b.x; s8[5] += b.y; s8[6] += b.z; s8[7] += b.w;
    m8[0] += a.x * mk; m8[1] += a.y * mk; m8[2] += a.z * mk; m8[3] += a.w * mk;
    m8[4] += b.x * mk; m8[5] += b.y * mk; m8[6] += b.z * mk; m8[7] += b.w * mk;
  }
  float vals[16];
#pragma unroll
  for (int e = 0; e < 8; ++e) { vals[e] = s8[e]; vals[8 + e] = m8[e]; }
#pragma unroll
  for (int k = 0; k < 16; ++k) {
    float v = vals[k];
    v += __shfl_xor(v, 1);  v += __shfl_xor(v, 2);  v += __shfl_xor(v, 4);
    v += __shfl_xor(v, 8);  v += __shfl_xor(v, 16); v += __shfl_xor(v, 32);
    vals[k] = v;
  }
  __shared__ float red[4][16];
  const int lane = tid & 63, wid = tid >> 6;
  if (lane == 0) {
#pragma unroll
    for (int k = 0; k < 16; ++k) red[wid][k] = vals[k];
  }
  __syncthreads();
  if (tid == 0) {
    float s[16];
#pragma unroll
    for (int k = 0; k < 16; ++k)
      s[k] = red[0][k] + red[1][k] + red[2][k] + red[3][k];
    float entropy_loss = 0.f;
#pragma unroll
    for (int e = 0; e < 8; ++e) {
      float rppe = s[e] / (float)M_TOK;
      entropy_loss += rppe * logf(rppe * 8.f + 1e-9f);
    }
    float tot = 0.f;
#pragma unroll
    for (int e = 0; e < 8; ++e) tot += s[8 + e] + 1e-9f;
    float imp_entropy = 0.f;
#pragma unroll
    for (int e = 0; e < 8; ++e) {
      float ipe = (s[8 + e] + 1e-9f) / tot;
      imp_entropy -= ipe * logf(ipe + 1e-9f);
    }
    aux_out[0] = entropy_loss - 0.1f * (imp_entropy / logf(8.f));
  }
}

// ---------------------------------------------------------------------------
extern "C" void kernel_launch(void* const* d_in, const int* in_sizes, int n_in,
                              void* d_out, int out_size, void* d_ws,
                              size_t ws_size, hipStream_t stream) {
  const float* x   = (const float*)d_in[0];
  const float* Wi1 = (const float*)d_in[1];
  const float* bi1 = (const float*)d_in[2];
  const float* Wi2 = (const float*)d_in[3];
  const float* bi2 = (const float*)d_in[4];
  const float* Wr1 = (const float*)d_in[5];
  const float* br1 = (const float*)d_in[6];
  const float* Wr2 = (const float*)d_in[7];
  const float* br2 = (const float*)d_in[8];
  const float* Wu1 = (const float*)d_in[9];
  const float* bu1 = (const float*)d_in[10];
  const float* Wu2 = (const float*)d_in[11];
  const float* bu2 = (const float*)d_in[12];

  float* out  = (float*)d_out;
  float* disp = out;
  float* comb = out + DISP_ELEMS;
  float* rp   = out + 2 * DISP_ELEMS;            // 32768
  float* aux  = out + 2 * DISP_ELEMS + 32768;    // 1
  float* imp  = aux + 1;                         // 4096

  // scratch layout (bytes):
  //   xh 16.78M | xl 16.78M | wTh 20.97M | wTl 20.97M | h_i 16.78M | h_r 33.55M | h_u 33.55M
  const size_t xh_b  = (size_t)M_TOK * HID * 2;
  const size_t wT_b  = (size_t)NTOT * HID * 2;
  const size_t hi_b  = (size_t)M_TOK * 1024 * 4;
  const size_t hr_b  = (size_t)M_TOK * 2048 * 4;
  const size_t need  = 2 * xh_b + 2 * wT_b + hi_b + 2 * hr_b + 256;
  char* scratch = (ws_size >= need) ? (char*)d_ws : (char*)comb;  // comb region is 201MB > 153MB

  unsigned short* xh  = (unsigned short*)scratch;
  unsigned short* xl  = (unsigned short*)(scratch + xh_b);
  unsigned short* wTh = (unsigned short*)(scratch + 2 * xh_b);
  unsigned short* wTl = (unsigned short*)(scratch + 2 * xh_b + wT_b);
  float* h_i = (float*)(scratch + 2 * xh_b + 2 * wT_b);
  float* h_r = h_i + (size_t)M_TOK * 1024;
  float* h_u = h_r + (size_t)M_TOK * 2048;
  int* flags = (int*)(comb + DISP_ELEMS - 16);

  // 1. zero disp + flags
  hipMemsetAsync(disp, 0, DISP_ELEMS * sizeof(float), stream);
  hipMemsetAsync(flags, 0, 16 * sizeof(float), stream);

  // 2. convert inputs to bf16 hi/lo (W transposed into concat [5120][2048])
  convert_x_k<<<(M_TOK * HID / 4) / 256, 256, 0, stream>>>(x, xh, xl);
  convert_wT_k<<<dim3(1024 / 32, HID / 32), 256, 0, stream>>>(Wi1, 1024, 0, wTh, wTl);
  convert_wT_k<<<dim3(2048 / 32, HID / 32), 256, 0, stream>>>(Wr1, 2048, 1024, wTh, wTl);
  convert_wT_k<<<dim3(2048 / 32, HID / 32), 256, 0, stream>>>(Wu1, 2048, 3072, wTh, wTl);

  // 3. fused split-bf16 MFMA GEMM for all three layer-1 matmuls
  gemm_split_k<<<dim3(NTOT / 128, M_TOK / 128), 256, 0, stream>>>(
      xh, xl, wTh, wTl, bi1, br1, bu1, h_i, h_r, h_u);

  // 4. router probs / importance / top-1 flags
  router_k<<<M_TOK, 256, 0, stream>>>(h_i, h_r, h_u, Wi2, bi2, Wr2, br2,
                                      Wu2, bu2, rp, imp, flags);

  // 5. zero comb (h/xh/wT in comb region are dead now), keep flag tail
  hipMemsetAsync(comb, 0, (DISP_ELEMS - 16) * sizeof(float), stream);

  // 6. scatter the 2 nonzeros per token
  scatter_k<<<(M_TOK + 255) / 256, 256, 0, stream>>>(rp, flags, disp, comb);

  // 7. zero the flag tail
  hipMemsetAsync(flags, 0, 16 * sizeof(float), stream);

  // 8. aux loss
  aux_k<<<1, 256, 0, stream>>>(rp, imp, aux);
}

// Round 3
// 458.312 us; speedup vs baseline: 2.7410x; 1.0076x over previous
//
#include <hip/hip_runtime.h>
#include <math.h>

#define M_TOK 4096           // B*S
#define HID   2048
#define NEXP  8
#define CAP   1536
#define DISP_ELEMS 50331648ull   // 4096*8*1536
#define NTOT  5120               // 1024 + 2048 + 2048 (concat N)

typedef __attribute__((ext_vector_type(8))) short bf16x8;
typedef __attribute__((ext_vector_type(4))) float f32x4;

__device__ __forceinline__ unsigned short f2bf(float f) {
  unsigned u = __float_as_uint(f);
  unsigned r = u + 0x7FFFu + ((u >> 16) & 1u);   // RNE (finite inputs)
  return (unsigned short)(r >> 16);
}
__device__ __forceinline__ float bf2f(unsigned short h) {
  return __uint_as_float(((unsigned)h) << 16);
}

__device__ __forceinline__ void gload16(const void* g, void* l) {
  __builtin_amdgcn_global_load_lds(
      (const __attribute__((address_space(1))) void*)g,
      (__attribute__((address_space(3))) void*)l, 16, 0, 0);
}

// ---------------------------------------------------------------------------
// x (fp32 [M][K]) -> x_hi, x_lo (bf16 [M][K])
// ---------------------------------------------------------------------------
__global__ __launch_bounds__(256)
void convert_x_k(const float* __restrict__ x, unsigned short* __restrict__ xh,
                 unsigned short* __restrict__ xl) {
  size_t i = ((size_t)blockIdx.x * 256 + threadIdx.x) * 4;
  float4 v = *reinterpret_cast<const float4*>(&x[i]);
  float f[4] = {v.x, v.y, v.z, v.w};
  unsigned short hh[4], ll[4];
#pragma unroll
  for (int j = 0; j < 4; ++j) {
    hh[j] = f2bf(f[j]);
    ll[j] = f2bf(f[j] - bf2f(hh[j]));
  }
  uint2 ph, pl;
  ph.x = hh[0] | ((unsigned)hh[1] << 16); ph.y = hh[2] | ((unsigned)hh[3] << 16);
  pl.x = ll[0] | ((unsigned)ll[1] << 16); pl.y = ll[2] | ((unsigned)ll[3] << 16);
  *reinterpret_cast<uint2*>(&xh[i]) = ph;
  *reinterpret_cast<uint2*>(&xl[i]) = pl;
}

// ---------------------------------------------------------------------------
// W (fp32 [K=2048][N]) -> W^T hi/lo (bf16 [rowOff+N][2048])
// ---------------------------------------------------------------------------
__global__ __launch_bounds__(256)
void convert_wT_k(const float* __restrict__ W, int N, int rowOff,
                  unsigned short* __restrict__ wTh,
                  unsigned short* __restrict__ wTl) {
  __shared__ float tile[32][33];
  const int k0 = blockIdx.y * 32;
  const int n0 = blockIdx.x * 32;
  const int tid = threadIdx.x;
  {
    int r = tid >> 3, c4 = (tid & 7) * 4;
    float4 v = *reinterpret_cast<const float4*>(&W[(size_t)(k0 + r) * N + n0 + c4]);
    tile[r][c4 + 0] = v.x; tile[r][c4 + 1] = v.y;
    tile[r][c4 + 2] = v.z; tile[r][c4 + 3] = v.w;
  }
  __syncthreads();
  int n = tid >> 3, kc = (tid & 7) * 4;
  unsigned short hh[4], ll[4];
#pragma unroll
  for (int j = 0; j < 4; ++j) {
    float f = tile[kc + j][n];
    hh[j] = f2bf(f);
    ll[j] = f2bf(f - bf2f(hh[j]));
  }
  size_t o = (size_t)(rowOff + n0 + n) * HID + k0 + kc;
  uint2 ph, pl;
  ph.x = hh[0] | ((unsigned)hh[1] << 16); ph.y = hh[2] | ((unsigned)hh[3] << 16);
  pl.x = ll[0] | ((unsigned)ll[1] << 16); pl.y = ll[2] | ((unsigned)ll[3] << 16);
  *reinterpret_cast<uint2*>(&wTh[o]) = ph;
  *reinterpret_cast<uint2*>(&wTl[o]) = pl;
}

// ---------------------------------------------------------------------------
// Split-bf16 GEMM: C = relu(A@W + b), A fp32-split (Ah+Al), W^T-split rows.
// 128x128 tile, BK=32, 256 thr (4 waves 2x2), 48 MFMA/wave/K-step.
// C = Ah@Bh + Ah@Bl + Al@Bh   (fp32 accum; lo*lo dropped ~2^-18)
//
// T2 bank-conflict fix (both-sides swizzle, rule #21):
//   LDS tile = [128 rows][4 slots of 16B], linear (gload_lds needs linear dest).
//   Physical slot q holds logical slot q ^ ((r>>1)&3):
//     - staging pre-swizzles the GLOBAL source k-offset
//     - ds_read XORs its slot address the same way
//   Spreads each quarter-wave's 16 lanes (same slot, rows r..r+15) over all
//   8 bank-groups: 2 lanes/group = conflict-free (m136).
// ---------------------------------------------------------------------------
__global__ __launch_bounds__(256)
void gemm_split_k(const unsigned short* __restrict__ Ah,
                  const unsigned short* __restrict__ Al,
                  const unsigned short* __restrict__ Bh,
                  const unsigned short* __restrict__ Bl,
                  const float* __restrict__ bi1, const float* __restrict__ br1,
                  const float* __restrict__ bu1, float* __restrict__ h_i,
                  float* __restrict__ h_r, float* __restrict__ h_u) {
  __shared__ unsigned short lds[16384];  // AH@0 AL@4096 BH@8192 BL@12288 (shorts)
  const int tid = threadIdx.x;
  const int lane = tid & 63;
  const int wave = tid >> 6;
  const int wr = wave >> 1, wc = wave & 1;
  const int ct = blockIdx.x;            // 0..39 col tile in concat-N
  const int row0 = blockIdx.y * 128;
  const int bcol0 = ct * 128;           // row in W^T concat

  f32x4 acc[4][4];
#pragma unroll
  for (int m = 0; m < 4; ++m)
#pragma unroll
    for (int n = 0; n < 4; ++n) acc[m][n] = (f32x4){0.f, 0.f, 0.f, 0.f};

  for (int k0 = 0; k0 < HID; k0 += 32) {
#pragma unroll
    for (int it = 0; it < 2; ++it) {
      int ix = it * 256 + tid;
      int r = ix >> 2, q = ix & 3;
      int qs = q ^ ((r >> 1) & 3);           // pre-swizzled source slot
      size_t ga = (size_t)(row0 + r) * HID + k0 + qs * 8;
      size_t gb = (size_t)(bcol0 + r) * HID + k0 + qs * 8;
      gload16(Ah + ga, &lds[ix * 8]);        // LDS dest stays linear
      gload16(Al + ga, &lds[4096 + ix * 8]);
      gload16(Bh + gb, &lds[8192 + ix * 8]);
      gload16(Bl + gb, &lds[12288 + ix * 8]);
    }
    __syncthreads();   // compiler drains vmcnt(0) before s_barrier

    bf16x8 ah[4], al[4], bh[4], bl[4];
    const int kk = (lane >> 4) * 8;          // logical slot * 8 shorts
#pragma unroll
    for (int m = 0; m < 4; ++m) {
      int rr = wr * 64 + m * 16 + (lane & 15);
      int ko = kk ^ (((rr >> 1) & 3) << 3);  // swizzled slot offset (shorts)
      ah[m] = *reinterpret_cast<const bf16x8*>(&lds[rr * 32 + ko]);
      al[m] = *reinterpret_cast<const bf16x8*>(&lds[4096 + rr * 32 + ko]);
    }
#pragma unroll
    for (int n = 0; n < 4; ++n) {
      int cc = wc * 64 + n * 16 + (lane & 15);
      int ko = kk ^ (((cc >> 1) & 3) << 3);
      bh[n] = *reinterpret_cast<const bf16x8*>(&lds[8192 + cc * 32 + ko]);
      bl[n] = *reinterpret_cast<const bf16x8*>(&lds[12288 + cc * 32 + ko]);
    }
#pragma unroll
    for (int m = 0; m < 4; ++m)
#pragma unroll
      for (int n = 0; n < 4; ++n) {
        acc[m][n] = __builtin_amdgcn_mfma_f32_16x16x32_bf16(ah[m], bh[n], acc[m][n], 0, 0, 0);
        acc[m][n] = __builtin_amdgcn_mfma_f32_16x16x32_bf16(ah[m], bl[n], acc[m][n], 0, 0, 0);
        acc[m][n] = __builtin_amdgcn_mfma_f32_16x16x32_bf16(al[m], bh[n], acc[m][n], 0, 0, 0);
      }
    __syncthreads();
  }

  float* C; const float* bias; int ldc, col0l;
  if (ct < 8)       { C = h_i; bias = bi1; ldc = 1024; col0l = ct * 128; }
  else if (ct < 24) { C = h_r; bias = br1; ldc = 2048; col0l = (ct - 8) * 128; }
  else              { C = h_u; bias = bu1; ldc = 2048; col0l = (ct - 24) * 128; }
#pragma unroll
  for (int n = 0; n < 4; ++n) {
    int cg = col0l + wc * 64 + n * 16 + (lane & 15);
    float bn = bias[cg];
#pragma unroll
    for (int m = 0; m < 4; ++m) {
      int rbase = row0 + wr * 64 + m * 16 + (lane >> 4) * 4;
#pragma unroll
      for (int j = 0; j < 4; ++j)
        C[(size_t)(rbase + j) * ldc + cg] = fmaxf(acc[m][n][j] + bn, 0.f);
    }
  }
}

// ---------------------------------------------------------------------------
// Per-token second layers + softmax + top-1 flag. One block per token.
// ---------------------------------------------------------------------------
__global__ __launch_bounds__(256)
void router_k(const float* __restrict__ h_i, const float* __restrict__ h_r,
              const float* __restrict__ h_u,
              const float* __restrict__ Wi2, const float* __restrict__ bi2,
              const float* __restrict__ Wr2, const float* __restrict__ br2,
              const float* __restrict__ Wu2, const float* __restrict__ bu2,
              float* __restrict__ router_probs, float* __restrict__ importance,
              int* __restrict__ expert_used) {
  const int t = blockIdx.x;
  const int tid = threadIdx.x;

  float acc_i;
  {
    float4 hv = *reinterpret_cast<const float4*>(&h_i[(size_t)t * 1024 + tid * 4]);
    float4 wv = *reinterpret_cast<const float4*>(&Wi2[tid * 4]);
    acc_i = hv.x * wv.x + hv.y * wv.y + hv.z * wv.z + hv.w * wv.w;
  }

  float accR[8], accU[8];
#pragma unroll
  for (int e = 0; e < 8; ++e) { accR[e] = 0.f; accU[e] = 0.f; }

  const int i0 = tid * 8;
  {
    float4 h0 = *reinterpret_cast<const float4*>(&h_r[(size_t)t * 2048 + i0]);
    float4 h1 = *reinterpret_cast<const float4*>(&h_r[(size_t)t * 2048 + i0 + 4]);
    float hr[8] = {h0.x, h0.y, h0.z, h0.w, h1.x, h1.y, h1.z, h1.w};
#pragma unroll
    for (int q = 0; q < 8; ++q) {
      float4 w0 = *reinterpret_cast<const float4*>(&Wr2[(size_t)(i0 + q) * 8]);
      float4 w1 = *reinterpret_cast<const float4*>(&Wr2[(size_t)(i0 + q) * 8 + 4]);
      accR[0] = fmaf(hr[q], w0.x, accR[0]); accR[1] = fmaf(hr[q], w0.y, accR[1]);
      accR[2] = fmaf(hr[q], w0.z, accR[2]); accR[3] = fmaf(hr[q], w0.w, accR[3]);
      accR[4] = fmaf(hr[q], w1.x, accR[4]); accR[5] = fmaf(hr[q], w1.y, accR[5]);
      accR[6] = fmaf(hr[q], w1.z, accR[6]); accR[7] = fmaf(hr[q], w1.w, accR[7]);
    }
  }
  {
    float4 h0 = *reinterpret_cast<const float4*>(&h_u[(size_t)t * 2048 + i0]);
    float4 h1 = *reinterpret_cast<const float4*>(&h_u[(size_t)t * 2048 + i0 + 4]);
    float hu[8] = {h0.x, h0.y, h0.z, h0.w, h1.x, h1.y, h1.z, h1.w};
#pragma unroll
    for (int q = 0; q < 8; ++q) {
      float4 w0 = *reinterpret_cast<const float4*>(&Wu2[(size_t)(i0 + q) * 8]);
      float4 w1 = *reinterpret_cast<const float4*>(&Wu2[(size_t)(i0 + q) * 8 + 4]);
      accU[0] = fmaf(hu[q], w0.x, accU[0]); accU[1] = fmaf(hu[q], w0.y, accU[1]);
      accU[2] = fmaf(hu[q], w0.z, accU[2]); accU[3] = fmaf(hu[q], w0.w, accU[3]);
      accU[4] = fmaf(hu[q], w1.x, accU[4]); accU[5] = fmaf(hu[q], w1.y, accU[5]);
      accU[6] = fmaf(hu[q], w1.z, accU[6]); accU[7] = fmaf(hu[q], w1.w, accU[7]);
    }
  }

  float vals[17];
  vals[0] = acc_i;
#pragma unroll
  for (int e = 0; e < 8; ++e) { vals[1 + e] = accR[e]; vals[9 + e] = accU[e]; }
#pragma unroll
  for (int k = 0; k < 17; ++k) {
    float v = vals[k];
    v += __shfl_xor(v, 1);  v += __shfl_xor(v, 2);  v += __shfl_xor(v, 4);
    v += __shfl_xor(v, 8);  v += __shfl_xor(v, 16); v += __shfl_xor(v, 32);
    vals[k] = v;
  }
  __shared__ float red[4][17];
  const int lane = tid & 63, wid = tid >> 6;
  if (lane == 0) {
#pragma unroll
    for (int k = 0; k < 17; ++k) red[wid][k] = vals[k];
  }
  __syncthreads();
  if (tid == 0) {
    float s[17];
#pragma unroll
    for (int k = 0; k < 17; ++k)
      s[k] = red[0][k] + red[1][k] + red[2][k] + red[3][k];
    float imp = 1.f / (1.f + expf(-(s[0] + bi2[0])));
    importance[t] = imp;
    bool useImp = imp > 0.5f;
    float logits[8];
#pragma unroll
    for (int e = 0; e < 8; ++e)
      logits[e] = useImp ? (s[1 + e] + br2[e]) : (s[9 + e] + bu2[e]);
    float mx = logits[0];
#pragma unroll
    for (int e = 1; e < 8; ++e) mx = fmaxf(mx, logits[e]);
    float ex[8], sum = 0.f;
#pragma unroll
    for (int e = 0; e < 8; ++e) { ex[e] = expf(logits[e] - mx); sum += ex[e]; }
    float p[8];
#pragma unroll
    for (int e = 0; e < 8; ++e) p[e] = ex[e] / sum;
#pragma unroll
    for (int e = 0; e < 8; ++e) router_probs[(size_t)t * 8 + e] = p[e];
    int e1 = 0; float p1 = p[0];
#pragma unroll
    for (int e = 1; e < 8; ++e) if (p[e] > p1) { p1 = p[e]; e1 = e; }
    expert_used[e1] = 1;   // benign race: all writers store 1
  }
}

// ---------------------------------------------------------------------------
__global__ __launch_bounds__(256)
void scatter_k(const float* __restrict__ router_probs,
               const int* __restrict__ expert_used,
               float* __restrict__ disp, float* __restrict__ comb) {
  int t = blockIdx.x * blockDim.x + threadIdx.x;
  if (t >= M_TOK) return;
  float4 a = *reinterpret_cast<const float4*>(&router_probs[(size_t)t * 8]);
  float4 b = *reinterpret_cast<const float4*>(&router_probs[(size_t)t * 8 + 4]);
  float p[8] = {a.x, a.y, a.z, a.w, b.x, b.y, b.z, b.w};
  int e1 = 0; float p1 = p[0];
#pragma unroll
  for (int e = 1; e < 8; ++e) if (p[e] > p1) { p1 = p[e]; e1 = e; }
  int e2 = 0; float p2 = -1.f;
#pragma unroll
  for (int e = 0; e < 8; ++e) {
    if (e == e1) continue;
    if (p[e] > p2) { p2 = p[e]; e2 = e; }
  }
  float s = p1 + p2;
  float p1n = p1 / s, p2n = p2 / s;
  size_t base = (size_t)t * NEXP * CAP;
  disp[base + (size_t)e1 * CAP + 0] = 1.f;
  comb[base + (size_t)e1 * CAP + 0] = p1n;
  int pos = expert_used[e2];
  disp[base + (size_t)e2 * CAP + pos] = 1.f;
  comb[base + (size_t)e2 * CAP + pos] = p2n;
}

// ---------------------------------------------------------------------------
__global__ __launch_bounds__(256)
void aux_k(const float* __restrict__ router_probs,
           const float* __restrict__ importance, float* __restrict__ aux_out) {
  const int tid = threadIdx.x;
  float s8[8], m8[8];
#pragma unroll
  for (int e = 0; e < 8; ++e) { s8[e] = 0.f; m8[e] = 0.f; }
  for (int t = tid; t < M_TOK; t += 256) {
    float4 a = *reinterpret_cast<const float4*>(&router_probs[(size_t)t * 8]);
    float4 b = *reinterpret_cast<const float4*>(&router_probs[(size_t)t * 8 + 4]);
    float mk = importance[t] > 0.5f ? 1.f : 0.f;
    s8[0] += a.x; s8[1] += a.y; s8[2] += a.z; s8[3] += a.w;
    s8[4] += b.x; s8[5] += b.y; s8[6] += b.z; s8[7] += b.w;
    m8[0] += a.x * mk; m8[1] += a.y * mk; m8[2] += a.z * mk; m8[3] += a.w * mk;
    m8[4] += b.x * mk; m8[5] += b.y * mk; m8[6] += b.z * mk; m8[7] += b.w * mk;
  }
  float vals[16];
#pragma unroll
  for (int e = 0; e < 8; ++e) { vals[e] = s8[e]; vals[8 + e] = m8[e]; }
#pragma unroll
  for (int k = 0; k < 16; ++k) {
    float v = vals[k];
    v += __shfl_xor(v, 1);  v += __shfl_xor(v, 2);  v += __shfl_xor(v, 4);
    v += __shfl_xor(v, 8);  v += __shfl_xor(v, 16); v += __shfl_xor(v, 32);
    vals[k] = v;
  }
  __shared__ float red[4][16];
  const int lane = tid & 63, wid = tid >> 6;
  if (lane == 0) {
#pragma unroll
    for (int k = 0; k < 16; ++k) red[wid][k] = vals[k];
  }
  __syncthreads();
  if (tid == 0) {
    float s[16];
#pragma unroll
    for (int k = 0; k < 16; ++k)
      s[k] = red[0][k] + red[1][k] + red[2][k] + red[3][k];
    float entropy_loss = 0.f;
#pragma unroll
    for (int e = 0; e < 8; ++e) {
      float rppe = s[e] / (float)M_TOK;
      entropy_loss += rppe * logf(rppe * 8.f + 1e-9f);
    }
    float tot = 0.f;
#pragma unroll
    for (int e = 0; e < 8; ++e) tot += s[8 + e] + 1e-9f;
    float imp_entropy = 0.f;
#pragma unroll
    for (int e = 0; e < 8; ++e) {
      float ipe = (s[8 + e] + 1e-9f) / tot;
      imp_entropy -= ipe * logf(ipe + 1e-9f);
    }
    aux_out[0] = entropy_loss - 0.1f * (imp_entropy / logf(8.f));
  }
}

// ---------------------------------------------------------------------------
extern "C" void kernel_launch(void* const* d_in, const int* in_sizes, int n_in,
                              void* d_out, int out_size, void* d_ws,
                              size_t ws_size, hipStream_t stream) {
  const float* x   = (const float*)d_in[0];
  const float* Wi1 = (const float*)d_in[1];
  const float* bi1 = (const float*)d_in[2];
  const float* Wi2 = (const float*)d_in[3];
  const float* bi2 = (const float*)d_in[4];
  const float* Wr1 = (const float*)d_in[5];
  const float* br1 = (const float*)d_in[6];
  const float* Wr2 = (const float*)d_in[7];
  const float* br2 = (const float*)d_in[8];
  const float* Wu1 = (const float*)d_in[9];
  const float* bu1 = (const float*)d_in[10];
  const float* Wu2 = (const float*)d_in[11];
  const float* bu2 = (const float*)d_in[12];

  float* out  = (float*)d_out;
  float* disp = out;
  float* comb = out + DISP_ELEMS;
  float* rp   = out + 2 * DISP_ELEMS;            // 32768
  float* aux  = out + 2 * DISP_ELEMS + 32768;    // 1
  float* imp  = aux + 1;                         // 4096

  // scratch layout (bytes):
  //   xh 16.78M | xl 16.78M | wTh 20.97M | wTl 20.97M | h_i 16.78M | h_r 33.55M | h_u 33.55M
  const size_t xh_b  = (size_t)M_TOK * HID * 2;
  const size_t wT_b  = (size_t)NTOT * HID * 2;
  const size_t hi_b  = (size_t)M_TOK * 1024 * 4;
  const size_t hr_b  = (size_t)M_TOK * 2048 * 4;
  const size_t need  = 2 * xh_b + 2 * wT_b + hi_b + 2 * hr_b + 256;
  const bool ws_ok = (ws_size >= need);
  char* scratch = ws_ok ? (char*)d_ws : (char*)comb;  // comb region 201MB > 153MB

  unsigned short* xh  = (unsigned short*)scratch;
  unsigned short* xl  = (unsigned short*)(scratch + xh_b);
  unsigned short* wTh = (unsigned short*)(scratch + 2 * xh_b);
  unsigned short* wTl = (unsigned short*)(scratch + 2 * xh_b + wT_b);
  float* h_i = (float*)(scratch + 2 * xh_b + 2 * wT_b);
  float* h_r = h_i + (size_t)M_TOK * 1024;
  float* h_u = h_r + (size_t)M_TOK * 2048;
  int* flags = (int*)(comb + DISP_ELEMS - 16);

  // 1. zero output region(s) + flags
  if (ws_ok) {
    // comb region is free -> one merged memset covers disp+comb+flags
    hipMemsetAsync(disp, 0, 2 * DISP_ELEMS * sizeof(float), stream);
  } else {
    hipMemsetAsync(disp, 0, DISP_ELEMS * sizeof(float), stream);
    hipMemsetAsync(flags, 0, 16 * sizeof(float), stream);
  }

  // 2. convert inputs to bf16 hi/lo (W transposed into concat [5120][2048])
  convert_x_k<<<(M_TOK * HID / 4) / 256, 256, 0, stream>>>(x, xh, xl);
  convert_wT_k<<<dim3(1024 / 32, HID / 32), 256, 0, stream>>>(Wi1, 1024, 0, wTh, wTl);
  convert_wT_k<<<dim3(2048 / 32, HID / 32), 256, 0, stream>>>(Wr1, 2048, 1024, wTh, wTl);
  convert_wT_k<<<dim3(2048 / 32, HID / 32), 256, 0, stream>>>(Wu1, 2048, 3072, wTh, wTl);

  // 3. fused split-bf16 MFMA GEMM for all three layer-1 matmuls
  gemm_split_k<<<dim3(NTOT / 128, M_TOK / 128), 256, 0, stream>>>(
      xh, xl, wTh, wTl, bi1, br1, bu1, h_i, h_r, h_u);

  // 4. router probs / importance / top-1 flags
  router_k<<<M_TOK, 256, 0, stream>>>(h_i, h_r, h_u, Wi2, bi2, Wr2, br2,
                                      Wu2, bu2, rp, imp, flags);

  // 5. zero comb if it was used as scratch (keep flag tail, just written)
  if (!ws_ok)
    hipMemsetAsync(comb, 0, (DISP_ELEMS - 16) * sizeof(float), stream);

  // 6. scatter the 2 nonzeros per token
  scatter_k<<<(M_TOK + 255) / 256, 256, 0, stream>>>(rp, flags, disp, comb);

  // 7. zero the flag tail
  hipMemsetAsync(flags, 0, 16 * sizeof(float), stream);

  // 8. aux loss
  aux_k<<<1, 256, 0, stream>>>(rp, imp, aux);
}

// Round 4
// 430.177 us; speedup vs baseline: 2.9203x; 1.0654x over previous
//
#include <hip/hip_runtime.h>
#include <math.h>

#define M_TOK 4096           // B*S
#define HID   2048
#define NEXP  8
#define CAP   1536
#define DISP_ELEMS 50331648ull   // 4096*8*1536
#define NTOT  5120               // 1024 + 2048 + 2048 (concat N)

typedef __attribute__((ext_vector_type(8))) short bf16x8;
typedef __attribute__((ext_vector_type(4))) float f32x4;

__device__ __forceinline__ unsigned short f2bf(float f) {
  unsigned u = __float_as_uint(f);
  unsigned r = u + 0x7FFFu + ((u >> 16) & 1u);   // RNE (finite inputs)
  return (unsigned short)(r >> 16);
}
__device__ __forceinline__ float bf2f(unsigned short h) {
  return __uint_as_float(((unsigned)h) << 16);
}

__device__ __forceinline__ void gload16(const void* g, void* l) {
  __builtin_amdgcn_global_load_lds(
      (const __attribute__((address_space(1))) void*)g,
      (__attribute__((address_space(3))) void*)l, 16, 0, 0);
}

// ---------------------------------------------------------------------------
// x (fp32 [M][K]) -> x_hi, x_lo (bf16 [M][K])
// ---------------------------------------------------------------------------
__global__ __launch_bounds__(256)
void convert_x_k(const float* __restrict__ x, unsigned short* __restrict__ xh,
                 unsigned short* __restrict__ xl) {
  size_t i = ((size_t)blockIdx.x * 256 + threadIdx.x) * 4;
  float4 v = *reinterpret_cast<const float4*>(&x[i]);
  float f[4] = {v.x, v.y, v.z, v.w};
  unsigned short hh[4], ll[4];
#pragma unroll
  for (int j = 0; j < 4; ++j) {
    hh[j] = f2bf(f[j]);
    ll[j] = f2bf(f[j] - bf2f(hh[j]));
  }
  uint2 ph, pl;
  ph.x = hh[0] | ((unsigned)hh[1] << 16); ph.y = hh[2] | ((unsigned)hh[3] << 16);
  pl.x = ll[0] | ((unsigned)ll[1] << 16); pl.y = ll[2] | ((unsigned)ll[3] << 16);
  *reinterpret_cast<uint2*>(&xh[i]) = ph;
  *reinterpret_cast<uint2*>(&xl[i]) = pl;
}

// ---------------------------------------------------------------------------
// W (fp32 [K=2048][N]) -> W^T hi/lo (bf16 [rowOff+N][2048])
// ---------------------------------------------------------------------------
__global__ __launch_bounds__(256)
void convert_wT_k(const float* __restrict__ W, int N, int rowOff,
                  unsigned short* __restrict__ wTh,
                  unsigned short* __restrict__ wTl) {
  __shared__ float tile[32][33];
  const int k0 = blockIdx.y * 32;
  const int n0 = blockIdx.x * 32;
  const int tid = threadIdx.x;
  {
    int r = tid >> 3, c4 = (tid & 7) * 4;
    float4 v = *reinterpret_cast<const float4*>(&W[(size_t)(k0 + r) * N + n0 + c4]);
    tile[r][c4 + 0] = v.x; tile[r][c4 + 1] = v.y;
    tile[r][c4 + 2] = v.z; tile[r][c4 + 3] = v.w;
  }
  __syncthreads();
  int n = tid >> 3, kc = (tid & 7) * 4;
  unsigned short hh[4], ll[4];
#pragma unroll
  for (int j = 0; j < 4; ++j) {
    float f = tile[kc + j][n];
    hh[j] = f2bf(f);
    ll[j] = f2bf(f - bf2f(hh[j]));
  }
  size_t o = (size_t)(rowOff + n0 + n) * HID + k0 + kc;
  uint2 ph, pl;
  ph.x = hh[0] | ((unsigned)hh[1] << 16); ph.y = hh[2] | ((unsigned)hh[3] << 16);
  pl.x = ll[0] | ((unsigned)ll[1] << 16); pl.y = ll[2] | ((unsigned)ll[3] << 16);
  *reinterpret_cast<uint2*>(&wTh[o]) = ph;
  *reinterpret_cast<uint2*>(&wTl[o]) = pl;
}

// ---------------------------------------------------------------------------
// Split-bf16 GEMM, deep-pipelined (T1+T2+T3+T4+T5):
//   C = relu(A@W + b) with A = Ah+Al, B^T = Bh+Bl (bf16 splits)
//   C = Ah@Bh + Ah@Bl + Al@Bh   (fp32 accum; lo*lo dropped ~2^-18)
// BM=128, BN=256, BK=32, 512 threads (8 waves, 2M x 4N), per-wave 64x64.
// LDS: TRIPLE buffer x 48KB = 144 KB. One s_barrier per K-tile; steady-state
// wait is vmcnt(6) (tile t+2's 6 loads/thread stay in flight) -- never 0.
// Slot-XOR swizzle (verified conflict-free in round 3) on both sides.
// ---------------------------------------------------------------------------
__global__ __launch_bounds__(512)
void gemm_split_k(const unsigned short* __restrict__ Ahg,
                  const unsigned short* __restrict__ Alg,
                  const unsigned short* __restrict__ Bhg,
                  const unsigned short* __restrict__ Blg,
                  const float* __restrict__ bi1, const float* __restrict__ br1,
                  const float* __restrict__ bu1, float* __restrict__ h_i,
                  float* __restrict__ h_r, float* __restrict__ h_u) {
  // buf layout (shorts): Ah@0(4096) Al@4096 Bh@8192(8192) Bl@16384 -> 24576
  __shared__ unsigned short lds[73728];          // 3 x 24576 shorts = 144 KB
  const int tid  = threadIdx.x;
  const int lane = tid & 63;
  const int wave = tid >> 6;
  const int lr   = lane & 15;
  const int slot = lane >> 4;                    // k-slot 0..3

  // XCD-chunked bijective swizzle (640 % 8 == 0)
  const int bid = blockIdx.x;
  const int swz = (bid & 7) * 80 + (bid >> 3);
  const int nt  = swz >> 5;                      // 0..19 (N panel of 256)
  const int mt  = swz & 31;                      // 0..31 (M panel of 128)
  const int row0  = mt * 128;
  const int bcol0 = nt * 256;

  // ---- per-thread staging sources (6 x 16B chunks per thread per K-tile)
  const unsigned short* gsrc[6];
  int ldsoff[6];
#pragma unroll
  for (int j = 0; j < 6; ++j) {
    int c = (wave * 6 + j) * 64 + lane;          // 0..3071
    int idx, r;
    const unsigned short* base;
    size_t rowbase;
    if (c < 1024) {                              // A hi/lo: 128 rows x 4 slots
      idx = c & 511; r = idx >> 2;
      base = (c < 512) ? Ahg : Alg;
      rowbase = (size_t)(row0 + r) * HID;
    } else {                                     // B hi/lo: 256 rows x 4 slots
      idx = (c - 1024) & 1023; r = idx >> 2;
      base = (c < 2048) ? Bhg : Blg;
      rowbase = (size_t)(bcol0 + r) * HID;
    }
    int q  = idx & 3;
    int qs = q ^ ((r >> 1) & 3);                 // pre-swizzled source slot
    gsrc[j] = base + rowbase + qs * 8;
    ldsoff[j] = c * 8;                           // linear LDS dest (shorts)
  }

  // ---- per-thread ds_read offsets (swizzled, conflict-free per r3 PMC)
  int aoff[4], boff[4];
#pragma unroll
  for (int m = 0; m < 4; ++m) {
    int ra = (wave >> 2) * 64 + m * 16 + lr;     // 0..127
    aoff[m] = ra * 32 + (slot ^ ((ra >> 1) & 3)) * 8;
  }
#pragma unroll
  for (int n = 0; n < 4; ++n) {
    int rb = (wave & 3) * 64 + n * 16 + lr;      // 0..255
    boff[n] = rb * 32 + (slot ^ ((rb >> 1) & 3)) * 8;
  }

  f32x4 acc[4][4];
#pragma unroll
  for (int m = 0; m < 4; ++m)
#pragma unroll
    for (int n = 0; n < 4; ++n) acc[m][n] = (f32x4){0.f, 0.f, 0.f, 0.f};

  auto stage = [&](int kt, unsigned short* bufbase) {
#pragma unroll
    for (int j = 0; j < 6; ++j)
      gload16(gsrc[j] + kt * 32, bufbase + ldsoff[j]);
  };
  auto computeTile = [&](const unsigned short* bb) {
    bf16x8 avh[4], avl[4], bvh[4], bvl[4];
#pragma unroll
    for (int m = 0; m < 4; ++m) {
      avh[m] = *reinterpret_cast<const bf16x8*>(&bb[aoff[m]]);
      avl[m] = *reinterpret_cast<const bf16x8*>(&bb[4096 + aoff[m]]);
    }
#pragma unroll
    for (int n = 0; n < 4; ++n) {
      bvh[n] = *reinterpret_cast<const bf16x8*>(&bb[8192 + boff[n]]);
      bvl[n] = *reinterpret_cast<const bf16x8*>(&bb[16384 + boff[n]]);
    }
    __builtin_amdgcn_s_setprio(1);
#pragma unroll
    for (int m = 0; m < 4; ++m)
#pragma unroll
      for (int n = 0; n < 4; ++n) {
        acc[m][n] = __builtin_amdgcn_mfma_f32_16x16x32_bf16(avh[m], bvh[n], acc[m][n], 0, 0, 0);
        acc[m][n] = __builtin_amdgcn_mfma_f32_16x16x32_bf16(avh[m], bvl[n], acc[m][n], 0, 0, 0);
        acc[m][n] = __builtin_amdgcn_mfma_f32_16x16x32_bf16(avl[m], bvh[n], acc[m][n], 0, 0, 0);
      }
    __builtin_amdgcn_s_setprio(0);
  };

  unsigned short* pb0 = &lds[0];
  unsigned short* pb1 = &lds[24576];
  unsigned short* pb2 = &lds[49152];

  // prologue: tiles 0 and 1 in flight
  stage(0, pb0);
  stage(1, pb1);
  asm volatile("s_waitcnt vmcnt(6)" ::: "memory");   // tile 0 landed
  __builtin_amdgcn_s_barrier();
  __builtin_amdgcn_sched_barrier(0);

  // steady state: 64 K-tiles total, stage t+2 while computing t
#pragma unroll 1
  for (int t = 0; t < 62; ++t) {
    stage(t + 2, pb2);
    computeTile(pb0);
    asm volatile("s_waitcnt vmcnt(6)" ::: "memory"); // tile t+1 landed; t+2 flying
    __builtin_amdgcn_s_barrier();
    __builtin_amdgcn_sched_barrier(0);
    unsigned short* tmp = pb0; pb0 = pb1; pb1 = pb2; pb2 = tmp;
  }
  // epilogue tiles 62, 63
  computeTile(pb0);
  asm volatile("s_waitcnt vmcnt(0)" ::: "memory");   // tile 63 landed
  __builtin_amdgcn_s_barrier();
  __builtin_amdgcn_sched_barrier(0);
  computeTile(pb1);

  // ---- epilogue: bias + relu + store
  float* C; const float* bias; int ldc, col0l;
  if (nt < 4)       { C = h_i; bias = bi1; ldc = 1024; col0l = nt * 256; }
  else if (nt < 12) { C = h_r; bias = br1; ldc = 2048; col0l = (nt - 4) * 256; }
  else              { C = h_u; bias = bu1; ldc = 2048; col0l = (nt - 12) * 256; }
#pragma unroll
  for (int n = 0; n < 4; ++n) {
    int cg = col0l + (wave & 3) * 64 + n * 16 + lr;
    float bn = bias[cg];
#pragma unroll
    for (int m = 0; m < 4; ++m) {
      int rbase = row0 + (wave >> 2) * 64 + m * 16 + slot * 4;
#pragma unroll
      for (int j = 0; j < 4; ++j)
        C[(size_t)(rbase + j) * ldc + cg] = fmaxf(acc[m][n][j] + bn, 0.f);
    }
  }
}

// ---------------------------------------------------------------------------
// Per-token second layers + softmax + top-1 flag. One block per token.
// ---------------------------------------------------------------------------
__global__ __launch_bounds__(256)
void router_k(const float* __restrict__ h_i, const float* __restrict__ h_r,
              const float* __restrict__ h_u,
              const float* __restrict__ Wi2, const float* __restrict__ bi2,
              const float* __restrict__ Wr2, const float* __restrict__ br2,
              const float* __restrict__ Wu2, const float* __restrict__ bu2,
              float* __restrict__ router_probs, float* __restrict__ importance,
              int* __restrict__ expert_used) {
  const int t = blockIdx.x;
  const int tid = threadIdx.x;

  float acc_i;
  {
    float4 hv = *reinterpret_cast<const float4*>(&h_i[(size_t)t * 1024 + tid * 4]);
    float4 wv = *reinterpret_cast<const float4*>(&Wi2[tid * 4]);
    acc_i = hv.x * wv.x + hv.y * wv.y + hv.z * wv.z + hv.w * wv.w;
  }

  float accR[8], accU[8];
#pragma unroll
  for (int e = 0; e < 8; ++e) { accR[e] = 0.f; accU[e] = 0.f; }

  const int i0 = tid * 8;
  {
    float4 h0 = *reinterpret_cast<const float4*>(&h_r[(size_t)t * 2048 + i0]);
    float4 h1 = *reinterpret_cast<const float4*>(&h_r[(size_t)t * 2048 + i0 + 4]);
    float hr[8] = {h0.x, h0.y, h0.z, h0.w, h1.x, h1.y, h1.z, h1.w};
#pragma unroll
    for (int q = 0; q < 8; ++q) {
      float4 w0 = *reinterpret_cast<const float4*>(&Wr2[(size_t)(i0 + q) * 8]);
      float4 w1 = *reinterpret_cast<const float4*>(&Wr2[(size_t)(i0 + q) * 8 + 4]);
      accR[0] = fmaf(hr[q], w0.x, accR[0]); accR[1] = fmaf(hr[q], w0.y, accR[1]);
      accR[2] = fmaf(hr[q], w0.z, accR[2]); accR[3] = fmaf(hr[q], w0.w, accR[3]);
      accR[4] = fmaf(hr[q], w1.x, accR[4]); accR[5] = fmaf(hr[q], w1.y, accR[5]);
      accR[6] = fmaf(hr[q], w1.z, accR[6]); accR[7] = fmaf(hr[q], w1.w, accR[7]);
    }
  }
  {
    float4 h0 = *reinterpret_cast<const float4*>(&h_u[(size_t)t * 2048 + i0]);
    float4 h1 = *reinterpret_cast<const float4*>(&h_u[(size_t)t * 2048 + i0 + 4]);
    float hu[8] = {h0.x, h0.y, h0.z, h0.w, h1.x, h1.y, h1.z, h1.w};
#pragma unroll
    for (int q = 0; q < 8; ++q) {
      float4 w0 = *reinterpret_cast<const float4*>(&Wu2[(size_t)(i0 + q) * 8]);
      float4 w1 = *reinterpret_cast<const float4*>(&Wu2[(size_t)(i0 + q) * 8 + 4]);
      accU[0] = fmaf(hu[q], w0.x, accU[0]); accU[1] = fmaf(hu[q], w0.y, accU[1]);
      accU[2] = fmaf(hu[q], w0.z, accU[2]); accU[3] = fmaf(hu[q], w0.w, accU[3]);
      accU[4] = fmaf(hu[q], w1.x, accU[4]); accU[5] = fmaf(hu[q], w1.y, accU[5]);
      accU[6] = fmaf(hu[q], w1.z, accU[6]); accU[7] = fmaf(hu[q], w1.w, accU[7]);
    }
  }

  float vals[17];
  vals[0] = acc_i;
#pragma unroll
  for (int e = 0; e < 8; ++e) { vals[1 + e] = accR[e]; vals[9 + e] = accU[e]; }
#pragma unroll
  for (int k = 0; k < 17; ++k) {
    float v = vals[k];
    v += __shfl_xor(v, 1);  v += __shfl_xor(v, 2);  v += __shfl_xor(v, 4);
    v += __shfl_xor(v, 8);  v += __shfl_xor(v, 16); v += __shfl_xor(v, 32);
    vals[k] = v;
  }
  __shared__ float red[4][17];
  const int lane = tid & 63, wid = tid >> 6;
  if (lane == 0) {
#pragma unroll
    for (int k = 0; k < 17; ++k) red[wid][k] = vals[k];
  }
  __syncthreads();
  if (tid == 0) {
    float s[17];
#pragma unroll
    for (int k = 0; k < 17; ++k)
      s[k] = red[0][k] + red[1][k] + red[2][k] + red[3][k];
    float imp = 1.f / (1.f + expf(-(s[0] + bi2[0])));
    importance[t] = imp;
    bool useImp = imp > 0.5f;
    float logits[8];
#pragma unroll
    for (int e = 0; e < 8; ++e)
      logits[e] = useImp ? (s[1 + e] + br2[e]) : (s[9 + e] + bu2[e]);
    float mx = logits[0];
#pragma unroll
    for (int e = 1; e < 8; ++e) mx = fmaxf(mx, logits[e]);
    float ex[8], sum = 0.f;
#pragma unroll
    for (int e = 0; e < 8; ++e) { ex[e] = expf(logits[e] - mx); sum += ex[e]; }
    float p[8];
#pragma unroll
    for (int e = 0; e < 8; ++e) p[e] = ex[e] / sum;
#pragma unroll
    for (int e = 0; e < 8; ++e) router_probs[(size_t)t * 8 + e] = p[e];
    int e1 = 0; float p1 = p[0];
#pragma unroll
    for (int e = 1; e < 8; ++e) if (p[e] > p1) { p1 = p[e]; e1 = e; }
    expert_used[e1] = 1;   // benign race: all writers store 1
  }
}

// ---------------------------------------------------------------------------
__global__ __launch_bounds__(256)
void scatter_k(const float* __restrict__ router_probs,
               const int* __restrict__ expert_used,
               float* __restrict__ disp, float* __restrict__ comb) {
  int t = blockIdx.x * blockDim.x + threadIdx.x;
  if (t >= M_TOK) return;
  float4 a = *reinterpret_cast<const float4*>(&router_probs[(size_t)t * 8]);
  float4 b = *reinterpret_cast<const float4*>(&router_probs[(size_t)t * 8 + 4]);
  float p[8] = {a.x, a.y, a.z, a.w, b.x, b.y, b.z, b.w};
  int e1 = 0; float p1 = p[0];
#pragma unroll
  for (int e = 1; e < 8; ++e) if (p[e] > p1) { p1 = p[e]; e1 = e; }
  int e2 = 0; float p2 = -1.f;
#pragma unroll
  for (int e = 0; e < 8; ++e) {
    if (e == e1) continue;
    if (p[e] > p2) { p2 = p[e]; e2 = e; }
  }
  float s = p1 + p2;
  float p1n = p1 / s, p2n = p2 / s;
  size_t base = (size_t)t * NEXP * CAP;
  disp[base + (size_t)e1 * CAP + 0] = 1.f;
  comb[base + (size_t)e1 * CAP + 0] = p1n;
  int pos = expert_used[e2];
  disp[base + (size_t)e2 * CAP + pos] = 1.f;
  comb[base + (size_t)e2 * CAP + pos] = p2n;
}

// ---------------------------------------------------------------------------
__global__ __launch_bounds__(256)
void aux_k(const float* __restrict__ router_probs,
           const float* __restrict__ importance, float* __restrict__ aux_out) {
  const int tid = threadIdx.x;
  float s8[8], m8[8];
#pragma unroll
  for (int e = 0; e < 8; ++e) { s8[e] = 0.f; m8[e] = 0.f; }
  for (int t = tid; t < M_TOK; t += 256) {
    float4 a = *reinterpret_cast<const float4*>(&router_probs[(size_t)t * 8]);
    float4 b = *reinterpret_cast<const float4*>(&router_probs[(size_t)t * 8 + 4]);
    float mk = importance[t] > 0.5f ? 1.f : 0.f;
    s8[0] += a.x; s8[1] += a.y; s8[2] += a.z; s8[3] += a.w;
    s8[4] += b.x; s8[5] += b.y; s8[6] += b.z; s8[7] += b.w;
    m8[0] += a.x * mk; m8[1] += a.y * mk; m8[2] += a.z * mk; m8[3] += a.w * mk;
    m8[4] += b.x * mk; m8[5] += b.y * mk; m8[6] += b.z * mk; m8[7] += b.w * mk;
  }
  float vals[16];
#pragma unroll
  for (int e = 0; e < 8; ++e) { vals[e] = s8[e]; vals[8 + e] = m8[e]; }
#pragma unroll
  for (int k = 0; k < 16; ++k) {
    float v = vals[k];
    v += __shfl_xor(v, 1);  v += __shfl_xor(v, 2);  v += __shfl_xor(v, 4);
    v += __shfl_xor(v, 8);  v += __shfl_xor(v, 16); v += __shfl_xor(v, 32);
    vals[k] = v;
  }
  __shared__ float red[4][16];
  const int lane = tid & 63, wid = tid >> 6;
  if (lane == 0) {
#pragma unroll
    for (int k = 0; k < 16; ++k) red[wid][k] = vals[k];
  }
  __syncthreads();
  if (tid == 0) {
    float s[16];
#pragma unroll
    for (int k = 0; k < 16; ++k)
      s[k] = red[0][k] + red[1][k] + red[2][k] + red[3][k];
    float entropy_loss = 0.f;
#pragma unroll
    for (int e = 0; e < 8; ++e) {
      float rppe = s[e] / (float)M_TOK;
      entropy_loss += rppe * logf(rppe * 8.f + 1e-9f);
    }
    float tot = 0.f;
#pragma unroll
    for (int e = 0; e < 8; ++e) tot += s[8 + e] + 1e-9f;
    float imp_entropy = 0.f;
#pragma unroll
    for (int e = 0; e < 8; ++e) {
      float ipe = (s[8 + e] + 1e-9f) / tot;
      imp_entropy -= ipe * logf(ipe + 1e-9f);
    }
    aux_out[0] = entropy_loss - 0.1f * (imp_entropy / logf(8.f));
  }
}

// ---------------------------------------------------------------------------
extern "C" void kernel_launch(void* const* d_in, const int* in_sizes, int n_in,
                              void* d_out, int out_size, void* d_ws,
                              size_t ws_size, hipStream_t stream) {
  const float* x   = (const float*)d_in[0];
  const float* Wi1 = (const float*)d_in[1];
  const float* bi1 = (const float*)d_in[2];
  const float* Wi2 = (const float*)d_in[3];
  const float* bi2 = (const float*)d_in[4];
  const float* Wr1 = (const float*)d_in[5];
  const float* br1 = (const float*)d_in[6];
  const float* Wr2 = (const float*)d_in[7];
  const float* br2 = (const float*)d_in[8];
  const float* Wu1 = (const float*)d_in[9];
  const float* bu1 = (const float*)d_in[10];
  const float* Wu2 = (const float*)d_in[11];
  const float* bu2 = (const float*)d_in[12];

  float* out  = (float*)d_out;
  float* disp = out;
  float* comb = out + DISP_ELEMS;
  float* rp   = out + 2 * DISP_ELEMS;            // 32768
  float* aux  = out + 2 * DISP_ELEMS + 32768;    // 1
  float* imp  = aux + 1;                         // 4096

  // scratch layout (bytes):
  //   xh 16.78M | xl 16.78M | wTh 20.97M | wTl 20.97M | h_i 16.78M | h_r 33.55M | h_u 33.55M
  const size_t xh_b  = (size_t)M_TOK * HID * 2;
  const size_t wT_b  = (size_t)NTOT * HID * 2;
  const size_t hi_b  = (size_t)M_TOK * 1024 * 4;
  const size_t hr_b  = (size_t)M_TOK * 2048 * 4;
  const size_t need  = 2 * xh_b + 2 * wT_b + hi_b + 2 * hr_b + 256;
  const bool ws_ok = (ws_size >= need);
  char* scratch = ws_ok ? (char*)d_ws : (char*)comb;  // comb region 201MB > 153MB

  unsigned short* xh  = (unsigned short*)scratch;
  unsigned short* xl  = (unsigned short*)(scratch + xh_b);
  unsigned short* wTh = (unsigned short*)(scratch + 2 * xh_b);
  unsigned short* wTl = (unsigned short*)(scratch + 2 * xh_b + wT_b);
  float* h_i = (float*)(scratch + 2 * xh_b + 2 * wT_b);
  float* h_r = h_i + (size_t)M_TOK * 1024;
  float* h_u = h_r + (size_t)M_TOK * 2048;
  int* flags = (int*)(comb + DISP_ELEMS - 16);

  // 1. zero output region(s) + flags
  if (ws_ok) {
    hipMemsetAsync(disp, 0, 2 * DISP_ELEMS * sizeof(float), stream);
  } else {
    hipMemsetAsync(disp, 0, DISP_ELEMS * sizeof(float), stream);
    hipMemsetAsync(flags, 0, 16 * sizeof(float), stream);
  }

  // 2. convert inputs to bf16 hi/lo (W transposed into concat [5120][2048])
  convert_x_k<<<(M_TOK * HID / 4) / 256, 256, 0, stream>>>(x, xh, xl);
  convert_wT_k<<<dim3(1024 / 32, HID / 32), 256, 0, stream>>>(Wi1, 1024, 0, wTh, wTl);
  convert_wT_k<<<dim3(2048 / 32, HID / 32), 256, 0, stream>>>(Wr1, 2048, 1024, wTh, wTl);
  convert_wT_k<<<dim3(2048 / 32, HID / 32), 256, 0, stream>>>(Wu1, 2048, 3072, wTh, wTl);

  // 3. fused split-bf16 MFMA GEMM (deep pipelined): 640 blocks x 512 thr
  gemm_split_k<<<640, 512, 0, stream>>>(xh, xl, wTh, wTl, bi1, br1, bu1,
                                        h_i, h_r, h_u);

  // 4. router probs / importance / top-1 flags
  router_k<<<M_TOK, 256, 0, stream>>>(h_i, h_r, h_u, Wi2, bi2, Wr2, br2,
                                      Wu2, bu2, rp, imp, flags);

  // 5. zero comb if it was used as scratch (keep flag tail, just written)
  if (!ws_ok)
    hipMemsetAsync(comb, 0, (DISP_ELEMS - 16) * sizeof(float), stream);

  // 6. scatter the 2 nonzeros per token
  scatter_k<<<(M_TOK + 255) / 256, 256, 0, stream>>>(rp, flags, disp, comb);

  // 7. zero the flag tail
  hipMemsetAsync(flags, 0, 16 * sizeof(float), stream);

  // 8. aux loss
  aux_k<<<1, 256, 0, stream>>>(rp, imp, aux);
}

// Round 6
// 413.026 us; speedup vs baseline: 3.0415x; 1.0415x over previous
//
#include <hip/hip_runtime.h>
#include <math.h>

#define M_TOK 4096           // B*S
#define HID   2048
#define NEXP  8
#define CAP   1536
#define DISP_ELEMS 50331648ull   // 4096*8*1536
#define NTOT  5120               // 1024 + 2048 + 2048 (concat N)
#define ZTOT4 25165824ull        // (2*DISP_ELEMS)/4 float4s

typedef __attribute__((ext_vector_type(8))) short bf16x8;
typedef __attribute__((ext_vector_type(4))) float f32x4;

__device__ __forceinline__ unsigned short f2bf(float f) {
  unsigned u = __float_as_uint(f);
  unsigned r = u + 0x7FFFu + ((u >> 16) & 1u);   // RNE (finite inputs)
  return (unsigned short)(r >> 16);
}
__device__ __forceinline__ float bf2f(unsigned short h) {
  return __uint_as_float(((unsigned)h) << 16);
}

__device__ __forceinline__ void gload16(const void* g, void* l) {
  __builtin_amdgcn_global_load_lds(
      (const __attribute__((address_space(1))) void*)g,
      (__attribute__((address_space(3))) void*)l, 16, 0, 0);
}
__device__ __forceinline__ bf16x8 ldsread(const unsigned short* p) {
  return *reinterpret_cast<const bf16x8*>(p);
}

// ---------------------------------------------------------------------------
// x (fp32 [M][K]) -> x_hi, x_lo (bf16 [M][K])
// ---------------------------------------------------------------------------
__global__ __launch_bounds__(256)
void convert_x_k(const float* __restrict__ x, unsigned short* __restrict__ xh,
                 unsigned short* __restrict__ xl) {
  size_t i = ((size_t)blockIdx.x * 256 + threadIdx.x) * 4;
  float4 v = *reinterpret_cast<const float4*>(&x[i]);
  float f[4] = {v.x, v.y, v.z, v.w};
  unsigned short hh[4], ll[4];
#pragma unroll
  for (int j = 0; j < 4; ++j) {
    hh[j] = f2bf(f[j]);
    ll[j] = f2bf(f[j] - bf2f(hh[j]));
  }
  uint2 ph, pl;
  ph.x = hh[0] | ((unsigned)hh[1] << 16); ph.y = hh[2] | ((unsigned)hh[3] << 16);
  pl.x = ll[0] | ((unsigned)ll[1] << 16); pl.y = ll[2] | ((unsigned)ll[3] << 16);
  *reinterpret_cast<uint2*>(&xh[i]) = ph;
  *reinterpret_cast<uint2*>(&xl[i]) = pl;
}

// ---------------------------------------------------------------------------
// W (fp32 [K=2048][N]) -> W^T hi/lo (bf16 [rowOff+N][2048])
// ---------------------------------------------------------------------------
__global__ __launch_bounds__(256)
void convert_wT_k(const float* __restrict__ W, int N, int rowOff,
                  unsigned short* __restrict__ wTh,
                  unsigned short* __restrict__ wTl) {
  __shared__ float tile[32][33];
  const int k0 = blockIdx.y * 32;
  const int n0 = blockIdx.x * 32;
  const int tid = threadIdx.x;
  {
    int r = tid >> 3, c4 = (tid & 7) * 4;
    float4 v = *reinterpret_cast<const float4*>(&W[(size_t)(k0 + r) * N + n0 + c4]);
    tile[r][c4 + 0] = v.x; tile[r][c4 + 1] = v.y;
    tile[r][c4 + 2] = v.z; tile[r][c4 + 3] = v.w;
  }
  __syncthreads();
  int n = tid >> 3, kc = (tid & 7) * 4;
  unsigned short hh[4], ll[4];
#pragma unroll
  for (int j = 0; j < 4; ++j) {
    float f = tile[kc + j][n];
    hh[j] = f2bf(f);
    ll[j] = f2bf(f - bf2f(hh[j]));
  }
  size_t o = (size_t)(rowOff + n0 + n) * HID + k0 + kc;
  uint2 ph, pl;
  ph.x = hh[0] | ((unsigned)hh[1] << 16); ph.y = hh[2] | ((unsigned)hh[3] << 16);
  pl.x = ll[0] | ((unsigned)ll[1] << 16); pl.y = ll[2] | ((unsigned)ll[3] << 16);
  *reinterpret_cast<uint2*>(&wTh[o]) = ph;
  *reinterpret_cast<uint2*>(&wTl[o]) = pl;
}

// ---------------------------------------------------------------------------
// Split-bf16 GEMM, 4-phase fine-interleaved pipeline (T1+T2+T3+T4+T5):
//   C = relu(A@W + b), A = Ah+Al, B^T = Bh+Bl (bf16 splits)
//   C = Ah@Bh + Ah@Bl + Al@Bh   (fp32 accum; lo*lo dropped ~2^-18)
// BM=128, BN=256, BK=32, 512 threads (8 waves, 2M x 4N), per-wave 64x64.
// LDS: triple buffer x 48KB = 144 KB; vmcnt(6) per K-tile (never 0 in loop).
// Per K-tile 4 phases: {ds_read quadrant frags | 2 stage issues | barrier |
// lgkmcnt(0) | setprio(1) 12 MFMA setprio(0) | barrier}. No redundant reads.
// Tail: fused nontemporal zero-fill of disp+comb (overlaps other blocks).
// ---------------------------------------------------------------------------
__global__ __launch_bounds__(512)
void gemm_split_k(const unsigned short* __restrict__ Ahg,
                  const unsigned short* __restrict__ Alg,
                  const unsigned short* __restrict__ Bhg,
                  const unsigned short* __restrict__ Blg,
                  const float* __restrict__ bi1, const float* __restrict__ br1,
                  const float* __restrict__ bu1, float* __restrict__ h_i,
                  float* __restrict__ h_r, float* __restrict__ h_u,
                  float* __restrict__ dzero) {
  // buf layout (shorts): Ah@0(4096) Al@4096 Bh@8192(8192) Bl@16384 -> 24576
  __shared__ unsigned short lds[73728];          // 3 x 24576 shorts = 144 KB
  const int tid  = threadIdx.x;
  const int lane = tid & 63;
  const int wave = tid >> 6;
  const int lr   = lane & 15;
  const int slot = lane >> 4;                    // k-slot 0..3

  // XCD-chunked bijective swizzle (640 % 8 == 0)
  const int bid = blockIdx.x;
  const int swz = (bid & 7) * 80 + (bid >> 3);
  const int nt  = swz >> 5;                      // 0..19 (N panel of 256)
  const int mt  = swz & 31;                      // 0..31 (M panel of 128)
  const int row0  = mt * 128;
  const int bcol0 = nt * 256;

  // ---- per-thread staging sources (6 x 16B chunks per thread per K-tile)
  const unsigned short* gsrc[6];
  int ldsoff[6];
#pragma unroll
  for (int j = 0; j < 6; ++j) {
    int c = (wave * 6 + j) * 64 + lane;          // 0..3071
    int idx, r;
    const unsigned short* base;
    size_t rowbase;
    if (c < 1024) {                              // A hi/lo: 128 rows x 4 slots
      idx = c & 511; r = idx >> 2;
      base = (c < 512) ? Ahg : Alg;
      rowbase = (size_t)(row0 + r) * HID;
    } else {                                     // B hi/lo: 256 rows x 4 slots
      idx = (c - 1024) & 1023; r = idx >> 2;
      base = (c < 2048) ? Bhg : Blg;
      rowbase = (size_t)(bcol0 + r) * HID;
    }
    int q  = idx & 3;
    int qs = q ^ ((r >> 1) & 3);                 // pre-swizzled source slot
    gsrc[j] = base + rowbase + qs * 8;
    ldsoff[j] = c * 8;                           // linear LDS dest (shorts)
  }

  // ---- per-thread ds_read offsets (swizzled, conflict-free per r3 PMC)
  int aoff[4], boff[4];
#pragma unroll
  for (int m = 0; m < 4; ++m) {
    int ra = (wave >> 2) * 64 + m * 16 + lr;     // 0..127
    aoff[m] = ra * 32 + (slot ^ ((ra >> 1) & 3)) * 8;
  }
#pragma unroll
  for (int n = 0; n < 4; ++n) {
    int rb = (wave & 3) * 64 + n * 16 + lr;      // 0..255
    boff[n] = rb * 32 + (slot ^ ((rb >> 1) & 3)) * 8;
  }

  f32x4 acc[4][4];
#pragma unroll
  for (int m = 0; m < 4; ++m)
#pragma unroll
    for (int n = 0; n < 4; ++n) acc[m][n] = (f32x4){0.f, 0.f, 0.f, 0.f};

  auto stage = [&](int kt, unsigned short* bufbase) {
#pragma unroll
    for (int j = 0; j < 6; ++j)
      gload16(gsrc[j] + kt * 32, bufbase + ldsoff[j]);
  };
  // simple (non-phased) tile compute for the epilogue tiles
  auto computeTile = [&](const unsigned short* bb) {
    bf16x8 avh[4], avl[4], bvh[4], bvl[4];
#pragma unroll
    for (int m = 0; m < 4; ++m) {
      avh[m] = ldsread(&bb[aoff[m]]);
      avl[m] = ldsread(&bb[4096 + aoff[m]]);
    }
#pragma unroll
    for (int n = 0; n < 4; ++n) {
      bvh[n] = ldsread(&bb[8192 + boff[n]]);
      bvl[n] = ldsread(&bb[16384 + boff[n]]);
    }
    __builtin_amdgcn_s_setprio(1);
#pragma unroll
    for (int m = 0; m < 4; ++m)
#pragma unroll
      for (int n = 0; n < 4; ++n) {
        acc[m][n] = __builtin_amdgcn_mfma_f32_16x16x32_bf16(avh[m], bvh[n], acc[m][n], 0, 0, 0);
        acc[m][n] = __builtin_amdgcn_mfma_f32_16x16x32_bf16(avh[m], bvl[n], acc[m][n], 0, 0, 0);
        acc[m][n] = __builtin_amdgcn_mfma_f32_16x16x32_bf16(avl[m], bvh[n], acc[m][n], 0, 0, 0);
      }
    __builtin_amdgcn_s_setprio(0);
  };

  unsigned short* pb0 = &lds[0];
  unsigned short* pb1 = &lds[24576];
  unsigned short* pb2 = &lds[49152];

  // prologue: tiles 0 and 1 in flight
  stage(0, pb0);
  stage(1, pb1);
  asm volatile("s_waitcnt vmcnt(6)" ::: "memory");   // tile 0 landed
  __builtin_amdgcn_s_barrier();
  __builtin_amdgcn_sched_barrier(0);

#define MFMA_CLUSTER(MB, NB)                                                   \
  __builtin_amdgcn_s_barrier();                                                \
  asm volatile("s_waitcnt lgkmcnt(0)" ::: "memory");                           \
  __builtin_amdgcn_sched_barrier(0);                                           \
  __builtin_amdgcn_s_setprio(1);                                               \
  _Pragma("unroll")                                                            \
  for (int m = MB; m < MB + 2; ++m)                                            \
    _Pragma("unroll")                                                          \
    for (int n = NB; n < NB + 2; ++n) {                                        \
      acc[m][n] = __builtin_amdgcn_mfma_f32_16x16x32_bf16(avh[m], bvh[n], acc[m][n], 0, 0, 0); \
      acc[m][n] = __builtin_amdgcn_mfma_f32_16x16x32_bf16(avh[m], bvl[n], acc[m][n], 0, 0, 0); \
      acc[m][n] = __builtin_amdgcn_mfma_f32_16x16x32_bf16(avl[m], bvh[n], acc[m][n], 0, 0, 0); \
    }                                                                          \
  __builtin_amdgcn_s_setprio(0);                                               \
  __builtin_amdgcn_s_barrier();

  // steady state: 64 K-tiles total; 4 fine phases per tile; stage t+2
#pragma unroll 1
  for (int t = 0; t < 62; ++t) {
    bf16x8 avh[4], avl[4], bvh[4], bvl[4];
    const int kt2 = (t + 2) * 32;
    // ---- phase 0: frags a01,b01 | stage chunks 0,1 | MFMA m01 x n01
#pragma unroll
    for (int m = 0; m < 2; ++m) {
      avh[m] = ldsread(&pb0[aoff[m]]);
      avl[m] = ldsread(&pb0[4096 + aoff[m]]);
    }
#pragma unroll
    for (int n = 0; n < 2; ++n) {
      bvh[n] = ldsread(&pb0[8192 + boff[n]]);
      bvl[n] = ldsread(&pb0[16384 + boff[n]]);
    }
    gload16(gsrc[0] + kt2, pb2 + ldsoff[0]);
    gload16(gsrc[1] + kt2, pb2 + ldsoff[1]);
    MFMA_CLUSTER(0, 0)
    // ---- phase 1: frags b23 | stage chunks 2,3 | MFMA m01 x n23
#pragma unroll
    for (int n = 2; n < 4; ++n) {
      bvh[n] = ldsread(&pb0[8192 + boff[n]]);
      bvl[n] = ldsread(&pb0[16384 + boff[n]]);
    }
    gload16(gsrc[2] + kt2, pb2 + ldsoff[2]);
    gload16(gsrc[3] + kt2, pb2 + ldsoff[3]);
    MFMA_CLUSTER(0, 2)
    // ---- phase 2: frags a23 | stage chunks 4,5 | MFMA m23 x n23
#pragma unroll
    for (int m = 2; m < 4; ++m) {
      avh[m] = ldsread(&pb0[aoff[m]]);
      avl[m] = ldsread(&pb0[4096 + aoff[m]]);
    }
    gload16(gsrc[4] + kt2, pb2 + ldsoff[4]);
    gload16(gsrc[5] + kt2, pb2 + ldsoff[5]);
    MFMA_CLUSTER(2, 2)
    // ---- phase 3: no reads | MFMA m23 x n01 | tile-boundary wait
    __builtin_amdgcn_s_setprio(1);
#pragma unroll
    for (int m = 2; m < 4; ++m)
#pragma unroll
      for (int n = 0; n < 2; ++n) {
        acc[m][n] = __builtin_amdgcn_mfma_f32_16x16x32_bf16(avh[m], bvh[n], acc[m][n], 0, 0, 0);
        acc[m][n] = __builtin_amdgcn_mfma_f32_16x16x32_bf16(avh[m], bvl[n], acc[m][n], 0, 0, 0);
        acc[m][n] = __builtin_amdgcn_mfma_f32_16x16x32_bf16(avl[m], bvh[n], acc[m][n], 0, 0, 0);
      }
    __builtin_amdgcn_s_setprio(0);
    asm volatile("s_waitcnt vmcnt(6)" ::: "memory"); // tile t+1 landed; t+2 flying
    __builtin_amdgcn_s_barrier();
    __builtin_amdgcn_sched_barrier(0);
    unsigned short* tmp = pb0; pb0 = pb1; pb1 = pb2; pb2 = tmp;
  }
  // epilogue tiles 62, 63
  computeTile(pb0);
  asm volatile("s_waitcnt vmcnt(0)" ::: "memory");   // tile 63 landed
  __builtin_amdgcn_s_barrier();
  __builtin_amdgcn_sched_barrier(0);
  computeTile(pb1);

  // ---- epilogue: bias + relu + store
  float* C; const float* bias; int ldc, col0l;
  if (nt < 4)       { C = h_i; bias = bi1; ldc = 1024; col0l = nt * 256; }
  else if (nt < 12) { C = h_r; bias = br1; ldc = 2048; col0l = (nt - 4) * 256; }
  else              { C = h_u; bias = bu1; ldc = 2048; col0l = (nt - 12) * 256; }
#pragma unroll
  for (int n = 0; n < 4; ++n) {
    int cg = col0l + (wave & 3) * 64 + n * 16 + lr;
    float bn = bias[cg];
#pragma unroll
    for (int m = 0; m < 4; ++m) {
      int rbase = row0 + (wave >> 2) * 64 + m * 16 + slot * 4;
#pragma unroll
      for (int j = 0; j < 4; ++j)
        C[(size_t)(rbase + j) * ldc + cg] = fmaxf(acc[m][n][j] + bn, 0.f);
    }
  }

  // ---- fused zero-fill of disp+comb (HBM headroom; overlaps other blocks)
  if (dzero) {
    f32x4 z = (f32x4){0.f, 0.f, 0.f, 0.f};
    f32x4* d4 = (f32x4*)dzero;
    for (size_t i = (size_t)bid * 512 + tid; i < ZTOT4; i += 640ull * 512ull)
      __builtin_nontemporal_store(z, d4 + i);
  }
}

// ---------------------------------------------------------------------------
// Per-token second layers + softmax + top-1 flag. One block per token.
// ---------------------------------------------------------------------------
__global__ __launch_bounds__(256)
void router_k(const float* __restrict__ h_i, const float* __restrict__ h_r,
              const float* __restrict__ h_u,
              const float* __restrict__ Wi2, const float* __restrict__ bi2,
              const float* __restrict__ Wr2, const float* __restrict__ br2,
              const float* __restrict__ Wu2, const float* __restrict__ bu2,
              float* __restrict__ router_probs, float* __restrict__ importance,
              int* __restrict__ expert_used) {
  const int t = blockIdx.x;
  const int tid = threadIdx.x;

  float acc_i;
  {
    float4 hv = *reinterpret_cast<const float4*>(&h_i[(size_t)t * 1024 + tid * 4]);
    float4 wv = *reinterpret_cast<const float4*>(&Wi2[tid * 4]);
    acc_i = hv.x * wv.x + hv.y * wv.y + hv.z * wv.z + hv.w * wv.w;
  }

  float accR[8], accU[8];
#pragma unroll
  for (int e = 0; e < 8; ++e) { accR[e] = 0.f; accU[e] = 0.f; }

  const int i0 = tid * 8;
  {
    float4 h0 = *reinterpret_cast<const float4*>(&h_r[(size_t)t * 2048 + i0]);
    float4 h1 = *reinterpret_cast<const float4*>(&h_r[(size_t)t * 2048 + i0 + 4]);
    float hr[8] = {h0.x, h0.y, h0.z, h0.w, h1.x, h1.y, h1.z, h1.w};
#pragma unroll
    for (int q = 0; q < 8; ++q) {
      float4 w0 = *reinterpret_cast<const float4*>(&Wr2[(size_t)(i0 + q) * 8]);
      float4 w1 = *reinterpret_cast<const float4*>(&Wr2[(size_t)(i0 + q) * 8 + 4]);
      accR[0] = fmaf(hr[q], w0.x, accR[0]); accR[1] = fmaf(hr[q], w0.y, accR[1]);
      accR[2] = fmaf(hr[q], w0.z, accR[2]); accR[3] = fmaf(hr[q], w0.w, accR[3]);
      accR[4] = fmaf(hr[q], w1.x, accR[4]); accR[5] = fmaf(hr[q], w1.y, accR[5]);
      accR[6] = fmaf(hr[q], w1.z, accR[6]); accR[7] = fmaf(hr[q], w1.w, accR[7]);
    }
  }
  {
    float4 h0 = *reinterpret_cast<const float4*>(&h_u[(size_t)t * 2048 + i0]);
    float4 h1 = *reinterpret_cast<const float4*>(&h_u[(size_t)t * 2048 + i0 + 4]);
    float hu[8] = {h0.x, h0.y, h0.z, h0.w, h1.x, h1.y, h1.z, h1.w};
#pragma unroll
    for (int q = 0; q < 8; ++q) {
      float4 w0 = *reinterpret_cast<const float4*>(&Wu2[(size_t)(i0 + q) * 8]);
      float4 w1 = *reinterpret_cast<const float4*>(&Wu2[(size_t)(i0 + q) * 8 + 4]);
      accU[0] = fmaf(hu[q], w0.x, accU[0]); accU[1] = fmaf(hu[q], w0.y, accU[1]);
      accU[2] = fmaf(hu[q], w0.z, accU[2]); accU[3] = fmaf(hu[q], w0.w, accU[3]);
      accU[4] = fmaf(hu[q], w1.x, accU[4]); accU[5] = fmaf(hu[q], w1.y, accU[5]);
      accU[6] = fmaf(hu[q], w1.z, accU[6]); accU[7] = fmaf(hu[q], w1.w, accU[7]);
    }
  }

  float vals[17];
  vals[0] = acc_i;
#pragma unroll
  for (int e = 0; e < 8; ++e) { vals[1 + e] = accR[e]; vals[9 + e] = accU[e]; }
#pragma unroll
  for (int k = 0; k < 17; ++k) {
    float v = vals[k];
    v += __shfl_xor(v, 1);  v += __shfl_xor(v, 2);  v += __shfl_xor(v, 4);
    v += __shfl_xor(v, 8);  v += __shfl_xor(v, 16); v += __shfl_xor(v, 32);
    vals[k] = v;
  }
  __shared__ float red[4][17];
  const int lane = tid & 63, wid = tid >> 6;
  if (lane == 0) {
#pragma unroll
    for (int k = 0; k < 17; ++k) red[wid][k] = vals[k];
  }
  __syncthreads();
  if (tid == 0) {
    float s[17];
#pragma unroll
    for (int k = 0; k < 17; ++k)
      s[k] = red[0][k] + red[1][k] + red[2][k] + red[3][k];
    float imp = 1.f / (1.f + expf(-(s[0] + bi2[0])));
    importance[t] = imp;
    bool useImp = imp > 0.5f;
    float logits[8];
#pragma unroll
    for (int e = 0; e < 8; ++e)
      logits[e] = useImp ? (s[1 + e] + br2[e]) : (s[9 + e] + bu2[e]);
    float mx = logits[0];
#pragma unroll
    for (int e = 1; e < 8; ++e) mx = fmaxf(mx, logits[e]);
    float ex[8], sum = 0.f;
#pragma unroll
    for (int e = 0; e < 8; ++e) { ex[e] = expf(logits[e] - mx); sum += ex[e]; }
    float p[8];
#pragma unroll
    for (int e = 0; e < 8; ++e) p[e] = ex[e] / sum;
#pragma unroll
    for (int e = 0; e < 8; ++e) router_probs[(size_t)t * 8 + e] = p[e];
    int e1 = 0; float p1 = p[0];
#pragma unroll
    for (int e = 1; e < 8; ++e) if (p[e] > p1) { p1 = p[e]; e1 = e; }
    expert_used[e1] = 1;   // benign race: all writers store 1
  }
}

// ---------------------------------------------------------------------------
__global__ __launch_bounds__(256)
void scatter_k(const float* __restrict__ router_probs,
               const int* __restrict__ expert_used,
               float* __restrict__ disp, float* __restrict__ comb) {
  int t = blockIdx.x * blockDim.x + threadIdx.x;
  if (t >= M_TOK) return;
  float4 a = *reinterpret_cast<const float4*>(&router_probs[(size_t)t * 8]);
  float4 b = *reinterpret_cast<const float4*>(&router_probs[(size_t)t * 8 + 4]);
  float p[8] = {a.x, a.y, a.z, a.w, b.x, b.y, b.z, b.w};
  int e1 = 0; float p1 = p[0];
#pragma unroll
  for (int e = 1; e < 8; ++e) if (p[e] > p1) { p1 = p[e]; e1 = e; }
  int e2 = 0; float p2 = -1.f;
#pragma unroll
  for (int e = 0; e < 8; ++e) {
    if (e == e1) continue;
    if (p[e] > p2) { p2 = p[e]; e2 = e; }
  }
  float s = p1 + p2;
  float p1n = p1 / s, p2n = p2 / s;
  size_t base = (size_t)t * NEXP * CAP;
  disp[base + (size_t)e1 * CAP + 0] = 1.f;
  comb[base + (size_t)e1 * CAP + 0] = p1n;
  int pos = expert_used[e2];
  disp[base + (size_t)e2 * CAP + pos] = 1.f;
  comb[base + (size_t)e2 * CAP + pos] = p2n;
}

// ---------------------------------------------------------------------------
// Aux loss + zero the flag tail (runs after scatter).
// ---------------------------------------------------------------------------
__global__ __launch_bounds__(256)
void aux_k(const float* __restrict__ router_probs,
           const float* __restrict__ importance, float* __restrict__ aux_out,
           float* __restrict__ flag_tail) {
  const int tid = threadIdx.x;
  if (tid < 16) flag_tail[tid] = 0.f;
  float s8[8], m8[8];
#pragma unroll
  for (int e = 0; e < 8; ++e) { s8[e] = 0.f; m8[e] = 0.f; }
  for (int t = tid; t < M_TOK; t += 256) {
    float4 a = *reinterpret_cast<const float4*>(&router_probs[(size_t)t * 8]);
    float4 b = *reinterpret_cast<const float4*>(&router_probs[(size_t)t * 8 + 4]);
    float mk = importance[t] > 0.5f ? 1.f : 0.f;
    s8[0] += a.x; s8[1] += a.y; s8[2] += a.z; s8[3] += a.w;
    s8[4] += b.x; s8[5] += b.y; s8[6] += b.z; s8[7] += b.w;
    m8[0] += a.x * mk; m8[1] += a.y * mk; m8[2] += a.z * mk; m8[3] += a.w * mk;
    m8[4] += b.x * mk; m8[5] += b.y * mk; m8[6] += b.z * mk; m8[7] += b.w * mk;
  }
  float vals[16];
#pragma unroll
  for (int e = 0; e < 8; ++e) { vals[e] = s8[e]; vals[8 + e] = m8[e]; }
#pragma unroll
  for (int k = 0; k < 16; ++k) {
    float v = vals[k];
    v += __shfl_xor(v, 1);  v += __shfl_xor(v, 2);  v += __shfl_xor(v, 4);
    v += __shfl_xor(v, 8);  v += __shfl_xor(v, 16); v += __shfl_xor(v, 32);
    vals[k] = v;
  }
  __shared__ float red[4][16];
  const int lane = tid & 63, wid = tid >> 6;
  if (lane == 0) {
#pragma unroll
    for (int k = 0; k < 16; ++k) red[wid][k] = vals[k];
  }
  __syncthreads();
  if (tid == 0) {
    float s[16];
#pragma unroll
    for (int k = 0; k < 16; ++k)
      s[k] = red[0][k] + red[1][k] + red[2][k] + red[3][k];
    float entropy_loss = 0.f;
#pragma unroll
    for (int e = 0; e < 8; ++e) {
      float rppe = s[e] / (float)M_TOK;
      entropy_loss += rppe * logf(rppe * 8.f + 1e-9f);
    }
    float tot = 0.f;
#pragma unroll
    for (int e = 0; e < 8; ++e) tot += s[8 + e] + 1e-9f;
    float imp_entropy = 0.f;
#pragma unroll
    for (int e = 0; e < 8; ++e) {
      float ipe = (s[8 + e] + 1e-9f) / tot;
      imp_entropy -= ipe * logf(ipe + 1e-9f);
    }
    aux_out[0] = entropy_loss - 0.1f * (imp_entropy / logf(8.f));
  }
}

// ---------------------------------------------------------------------------
extern "C" void kernel_launch(void* const* d_in, const int* in_sizes, int n_in,
                              void* d_out, int out_size, void* d_ws,
                              size_t ws_size, hipStream_t stream) {
  const float* x   = (const float*)d_in[0];
  const float* Wi1 = (const float*)d_in[1];
  const float* bi1 = (const float*)d_in[2];
  const float* Wi2 = (const float*)d_in[3];
  const float* bi2 = (const float*)d_in[4];
  const float* Wr1 = (const float*)d_in[5];
  const float* br1 = (const float*)d_in[6];
  const float* Wr2 = (const float*)d_in[7];
  const float* br2 = (const float*)d_in[8];
  const float* Wu1 = (const float*)d_in[9];
  const float* bu1 = (const float*)d_in[10];
  const float* Wu2 = (const float*)d_in[11];
  const float* bu2 = (const float*)d_in[12];

  float* out  = (float*)d_out;
  float* disp = out;
  float* comb = out + DISP_ELEMS;
  float* rp   = out + 2 * DISP_ELEMS;            // 32768
  float* aux  = out + 2 * DISP_ELEMS + 32768;    // 1
  float* imp  = aux + 1;                         // 4096

  // scratch layout (bytes):
  //   xh 16.78M | xl 16.78M | wTh 20.97M | wTl 20.97M | h_i 16.78M | h_r 33.55M | h_u 33.55M
  const size_t xh_b  = (size_t)M_TOK * HID * 2;
  const size_t wT_b  = (size_t)NTOT * HID * 2;
  const size_t hi_b  = (size_t)M_TOK * 1024 * 4;
  const size_t hr_b  = (size_t)M_TOK * 2048 * 4;
  const size_t need  = 2 * xh_b + 2 * wT_b + hi_b + 2 * hr_b + 256;
  const bool ws_ok = (ws_size >= need);
  char* scratch = ws_ok ? (char*)d_ws : (char*)comb;  // comb region 201MB > 153MB

  unsigned short* xh  = (unsigned short*)scratch;
  unsigned short* xl  = (unsigned short*)(scratch + xh_b);
  unsigned short* wTh = (unsigned short*)(scratch + 2 * xh_b);
  unsigned short* wTl = (unsigned short*)(scratch + 2 * xh_b + wT_b);
  float* h_i = (float*)(scratch + 2 * xh_b + 2 * wT_b);
  float* h_r = h_i + (size_t)M_TOK * 1024;
  float* h_u = h_r + (size_t)M_TOK * 2048;
  int* flags = (int*)(comb + DISP_ELEMS - 16);

  // 1. zeroing: if ws_ok, gemm's fused tail zeroes disp+comb (incl. flag
  //    tail) before router runs. Otherwise fall back to memsets.
  if (!ws_ok) {
    (void)hipMemsetAsync(disp, 0, DISP_ELEMS * sizeof(float), stream);
    (void)hipMemsetAsync(flags, 0, 16 * sizeof(float), stream);
  }

  // 2. convert inputs to bf16 hi/lo (W transposed into concat [5120][2048])
  convert_x_k<<<(M_TOK * HID / 4) / 256, 256, 0, stream>>>(x, xh, xl);
  convert_wT_k<<<dim3(1024 / 32, HID / 32), 256, 0, stream>>>(Wi1, 1024, 0, wTh, wTl);
  convert_wT_k<<<dim3(2048 / 32, HID / 32), 256, 0, stream>>>(Wr1, 2048, 1024, wTh, wTl);
  convert_wT_k<<<dim3(2048 / 32, HID / 32), 256, 0, stream>>>(Wu1, 2048, 3072, wTh, wTl);

  // 3. fused split-bf16 MFMA GEMM (4-phase pipeline): 640 blocks x 512 thr
  gemm_split_k<<<640, 512, 0, stream>>>(xh, xl, wTh, wTl, bi1, br1, bu1,
                                        h_i, h_r, h_u,
                                        ws_ok ? disp : (float*)nullptr);

  // 4. router probs / importance / top-1 flags
  router_k<<<M_TOK, 256, 0, stream>>>(h_i, h_r, h_u, Wi2, bi2, Wr2, br2,
                                      Wu2, bu2, rp, imp, flags);

  // 5. zero comb if it was used as scratch (keep flag tail, just written)
  if (!ws_ok)
    (void)hipMemsetAsync(comb, 0, (DISP_ELEMS - 16) * sizeof(float), stream);

  // 6. scatter the 2 nonzeros per token
  scatter_k<<<(M_TOK + 255) / 256, 256, 0, stream>>>(rp, flags, disp, comb);

  // 7. aux loss + flag-tail zeroing
  aux_k<<<1, 256, 0, stream>>>(rp, imp, aux, (float*)flags);
}